// Round 12
// baseline (1889.579 us; speedup 1.0000x reference)
//
#include <hip/hip_runtime.h>
#include <hip/hip_bf16.h>

typedef short v8s __attribute__((ext_vector_type(8)));
typedef float v4f __attribute__((ext_vector_type(4)));
typedef unsigned int u32;
typedef unsigned int u32x4 __attribute__((ext_vector_type(4)));
typedef unsigned short u16;
typedef unsigned long long u64;

// ---------- helpers ----------
__device__ __forceinline__ u16 f2bf(float f) {
    union { float f; u32 u; } x; x.f = f;
    u32 r = x.u + 0x7fffu + ((x.u >> 16) & 1u);   // RNE
    return (u16)(r >> 16);
}
__device__ __forceinline__ float bf2f(u16 s) {
    union { u32 u; float f; } x; x.u = ((u32)s) << 16;
    return x.f;
}
__device__ __forceinline__ float sigmoidf_(float x) { return 1.f / (1.f + __expf(-x)); }
__device__ __forceinline__ float tanh_fast(float x) {
    float t = fminf(fmaxf(x, -15.f), 15.f);
    float e = __expf(2.f * t);
    return (e - 1.f) / (e + 1.f);
}

// ---------- prep kernels ----------
__global__ __launch_bounds__(256) void xbf_kernel(const float* __restrict__ x, u16* __restrict__ xbf, int n) {
    int i = (blockIdx.x * 256 + threadIdx.x) * 4;
    if (i + 3 < n) {
        float4 v = *(const float4*)(x + i);
        u16* d = xbf + i;
        d[0] = f2bf(v.x); d[1] = f2bf(v.y); d[2] = f2bf(v.z); d[3] = f2bf(v.w);
    }
}

// W1[n][tap*2048+d] = n<512 ? wb[n,d,tap] : wr[n-512,d,tap]
// W2[n][tap*2048+d] = n<512 ? wa[n,d,tap] : wr[n-512,d,tap+5]
__global__ __launch_bounds__(256) void packw_kernel(const float* __restrict__ wb, const float* __restrict__ wa,
                                                    const float* __restrict__ wr, u16* __restrict__ W1, u16* __restrict__ W2) {
    long e = ((long)blockIdx.x * 256 + threadIdx.x) * 4;    // < 2*1024*10240
    int which = e >= (1024L * 10240) ? 1 : 0;
    long rem = e - (long)which * 1024 * 10240;
    int n = (int)(rem / 10240);
    int kap = (int)(rem % 10240);
    int tap = kap >> 11, d = kap & 2047;
    u16 o[4];
    if (n < 512) {
        const float* src = which ? wa : wb;
#pragma unroll
        for (int q = 0; q < 4; ++q) o[q] = f2bf(src[(long)n * 10240 + (d + q) * 5 + tap]);
    } else {
        const float* src = wr + (long)(n - 512) * 20480 + tap + (which ? 5 : 0);
#pragma unroll
        for (int q = 0; q < 4; ++q) o[q] = f2bf(src[(d + q) * 10]);
    }
    *(u64*)((which ? W2 : W1) + rem) = *(const u64*)o;
}

// wihpad[(dir*2048+g)][k] (K padded 513->576)
__global__ __launch_bounds__(256) void packwih_kernel(const float* __restrict__ wf, const float* __restrict__ wr,
                                                      u16* __restrict__ Bp) {
    int idx = blockIdx.x * 256 + threadIdx.x;               // < 4096*576
    int n = idx / 576, kap = idx % 576;
    int dir = n >> 11, g = n & 2047;
    const float* src = dir ? wr : wf;
    float v = (kap < 513) ? src[(long)g * 513 + kap] : 0.f;
    Bp[idx] = f2bf(v);
}

__global__ __launch_bounds__(256) void packwhh_kernel(const float* __restrict__ whf, const float* __restrict__ whr,
                                                      u16* __restrict__ W) {
    int idx = blockIdx.x * 256 + threadIdx.x;               // < 2*2048*512 = 2^21
    int dir = idx >> 20;
    float v = dir ? whr[idx & 1048575] : whf[idx];
    W[idx] = f2bf(v);
}

// bsum + hbuf tag clear (must run every launch: graph replays reuse hbuf)
__global__ __launch_bounds__(256) void misc_kernel(const float* __restrict__ bihf, const float* __restrict__ bhhf,
                                                   const float* __restrict__ bihr, const float* __restrict__ bhhr,
                                                   float* __restrict__ bsum, u64* __restrict__ hbuf) {
    int i = blockIdx.x * 256 + threadIdx.x;                 // grid covers 4096 + 16384
    if (i < 2048) bsum[i] = bihf[i] + bhhf[i];
    else if (i < 4096) bsum[i] = bihr[i - 2048] + bhhr[i - 2048];
    else if (i < 4096 + 16384) hbuf[i - 4096] = 0xFFFFFFFF00000000ULL;
}

// ---------- bf16 GEMM: C(MxN) = A(MxK,bf16; strided rows) * B(NxK,bf16)^T ----------
// row offset (elements) of logical row m: (m/row_div)*row_mul1 + (m%row_div)*row_mul2 + row_base
// grid divisible by 8 (bijective XCD swizzle).
template <int OUTBF>
__global__ __launch_bounds__(256) void gemm_bf16(const u16* __restrict__ A, const u16* __restrict__ B,
                                                 void* __restrict__ Cv, int M, int N, int K, int ldc,
                                                 int row_div, u32 row_mul1, u32 row_mul2, u32 row_base) {
    __shared__ u16 ldsA[128 * 64];
    __shared__ u16 ldsB[128 * 64];
    const int ntn = N >> 7;
    const int nwg = gridDim.x;
    const int bid = blockIdx.x;
    const int swz = (bid & 7) * (nwg >> 3) + (bid >> 3);
    const int tm = swz / ntn, tn = swz % ntn;
    const int tid = threadIdx.x, lane = tid & 63, wv = tid >> 6;
    const int wm = wv >> 1, wn = wv & 1;
    const int qbase = wv * 4;

    u32 asrc[4], bsrc[4];
#pragma unroll
    for (int it = 0; it < 4; ++it) {
        int q = qbase + it;
        int r = q * 8 + (lane >> 3);
        int cb = ((lane & 7) * 16) ^ ((r & 7) << 4);
        int m = tm * 128 + r; if (m > M - 1) m = M - 1;
        asrc[it] = row_base + (u32)(m / row_div) * row_mul1 + (u32)(m % row_div) * row_mul2 + (u32)(cb >> 1);
        int n = tn * 128 + r;
        bsrc[it] = (u32)n * (u32)K + (u32)(cb >> 1);
    }

    v4f acc[4][4];
#pragma unroll
    for (int i = 0; i < 4; ++i)
#pragma unroll
        for (int j = 0; j < 4; ++j) acc[i][j] = (v4f){0.f, 0.f, 0.f, 0.f};

    const int KT = K >> 6;
    for (int kt = 0; kt < KT; ++kt) {
        const int k0 = kt << 6;
#pragma unroll
        for (int it = 0; it < 4; ++it) {
            int q = qbase + it;
            __builtin_amdgcn_global_load_lds(
                (const __attribute__((address_space(1))) u32*)(A + asrc[it] + k0),
                (__attribute__((address_space(3))) u32*)((char*)ldsA + q * 1024), 16, 0, 0);
            __builtin_amdgcn_global_load_lds(
                (const __attribute__((address_space(1))) u32*)(B + bsrc[it] + k0),
                (__attribute__((address_space(3))) u32*)((char*)ldsB + q * 1024), 16, 0, 0);
        }
        __syncthreads();
#pragma unroll
        for (int kk = 0; kk < 2; ++kk) {
            v8s af[4], bfr[4];
#pragma unroll
            for (int i = 0; i < 4; ++i) {
                int row = wm * 64 + i * 16 + (lane & 15);
                int cbyte = (kk * 64 + ((lane >> 4) * 16)) ^ ((row & 7) << 4);
                af[i] = *(const v8s*)((const char*)ldsA + row * 128 + cbyte);
                int rn = wn * 64 + i * 16 + (lane & 15);
                int cbn = (kk * 64 + ((lane >> 4) * 16)) ^ ((rn & 7) << 4);
                bfr[i] = *(const v8s*)((const char*)ldsB + rn * 128 + cbn);
            }
#pragma unroll
            for (int i = 0; i < 4; ++i)
#pragma unroll
                for (int j = 0; j < 4; ++j)
                    acc[i][j] = __builtin_amdgcn_mfma_f32_16x16x32_bf16(af[i], bfr[j], acc[i][j], 0, 0, 0);
        }
        __syncthreads();
    }
#pragma unroll
    for (int i = 0; i < 4; ++i)
#pragma unroll
        for (int j = 0; j < 4; ++j)
#pragma unroll
            for (int r = 0; r < 4; ++r) {
                int m = tm * 128 + wm * 64 + i * 16 + (lane >> 4) * 4 + r;
                int n = tn * 128 + wn * 64 + j * 16 + (lane & 15);
                if (m < M) {
                    if (OUTBF) ((u16*)Cv)[(long)m * ldc + n] = f2bf(acc[i][j][r]);
                    else       ((float*)Cv)[(long)m * ldc + n] = acc[i][j][r];
                }
            }
}

// ---------- combine: build seq (bf16, padded K=576, row = t*16+b) ----------
__global__ __launch_bounds__(256) void combine_kernel(const float* __restrict__ G1, const float* __restrict__ G2,
                                                      const float* __restrict__ bb, const float* __restrict__ ba,
                                                      const float* __restrict__ br, u16* __restrict__ seqpad) {
    int m = blockIdx.x;                    // b*502 + t
    int b = m / 502, t = m % 502;
    int tid = threadIdx.x;
    const float* g1 = G1 + (long)m * 1024;
    const float* g2 = G2 + (long)m * 1024;
    u16* dst = seqpad + (long)(t * 16 + b) * 576;
    float part = 0.f;
#pragma unroll
    for (int rep = 0; rep < 2; ++rep) {
        int u = tid + rep * 256;
        float db = g1[u] + bb[u];
        float da = g2[u] + ba[u];
        part += db * da;
        float vr = g1[512 + u] + g2[512 + u] + br[u];
        dst[u] = f2bf(vr);
    }
#pragma unroll
    for (int off = 32; off; off >>= 1) part += __shfl_down(part, off, 64);
    __shared__ float red[4];
    if ((tid & 63) == 0) red[tid >> 6] = part;
    __syncthreads();
    if (tid == 0) dst[512] = f2bf(red[0] + red[1] + red[2] + red[3]);
    if (tid >= 1 && tid < 64) dst[512 + tid] = 0;
}

// ---------- persistent bidirectional LSTM ----------
// 16 WGs x 512 threads: dir = wg>>3, slice j = wg&7 (64 units/WG, 8 waves).
// Wave w: gate g = w&3, unit-half = w>>2 (32 units) — per-wave structure identical to R9
// (bf[2][16] = 128 regs, 2x2 MFMA chains, gls exchange). Consumer fan-in halves:
// 8 WGs/dir x 32KB per poll round (was 16 x 32KB). Tagged-u64 protocol, dwordx4 sc1 polls.
__global__ __launch_bounds__(512, 1) void lstm_kernel(const u16* __restrict__ P, const u16* __restrict__ whhbf,
                                                      const float* __restrict__ bsum, u64* hbuf,
                                                      u16* __restrict__ hs) {
    const int wg = blockIdx.x;
    const int dir = wg >> 3, j = wg & 7;
    const int tid = threadIdx.x, lane = tid & 63, w = tid >> 6;
    const int g = w & 3, half = w >> 2;
    __shared__ u16 hls[16 * 512];          // h (batch x 512) bf16, XOR-swizzled rows
    __shared__ float gls[4][16][64];       // gate type x batch x unit(64 per WG)

    v8s bf[2][16];                          // whh^T fragments resident all 502 steps
    const u16* whd = whhbf + (long)dir * 2048 * 512;
#pragma unroll
    for (int nt = 0; nt < 2; ++nt) {
        int n = g * 512 + j * 64 + half * 32 + nt * 16 + (lane & 15);
#pragma unroll
        for (int kt = 0; kt < 16; ++kt)
            bf[nt][kt] = *(const v8s*)(whd + (long)n * 512 + kt * 32 + ((lane >> 4) * 8));
    }

    for (int i = tid; i < 8192; i += 512) hls[i] = 0;

    const int b_ = tid >> 5;                // batch row (0..15)
    const int p_ = tid & 31;                // unit pair (0..31)
    const int u_ = p_ * 2;
    float c0 = 0.f, c1 = 0.f;
    u64* hb = hbuf + dir * 2 * 4096;
    const int col0 = g * 512 + j * 64 + half * 32 + (lane & 15);
    const float bs0 = bsum[dir * 2048 + col0];
    const float bs1 = bsum[dir * 2048 + col0 + 16];
    const u16* Pd = P + dir * 2048;

    // prefetch P for s=0
    float pv[2][4];
    {
        int tau = dir ? 501 : 0;
#pragma unroll
        for (int nt = 0; nt < 2; ++nt)
#pragma unroll
            for (int r = 0; r < 4; ++r)
                pv[nt][r] = bf2f(Pd[(long)(tau * 16 + ((lane >> 4) * 4 + r)) * 4096 + col0 + nt * 16]);
    }
    __syncthreads();

    for (int s = 0; s < 502; ++s) {
        const int tau = dir ? (501 - s) : s;
        if (s > 0) {
            const u64* slotp = hb + ((s - 1) & 1) * 4096;
            const u32 want = (u32)(s - 1);
            u64 base = (u64)slotp + (u64)tid * 16;           // thread reads words tid*2 + rep*1024 (+0/1)
            u64 a0 = base, a1 = base + 8192, a2 = base + 16384, a3 = base + 24576;
            u32x4 w0, w1, w2, w3;
            for (;;) {
                asm volatile(
                    "global_load_dwordx4 %[w0], %[a0], off sc1\n\t"
                    "global_load_dwordx4 %[w1], %[a1], off sc1\n\t"
                    "global_load_dwordx4 %[w2], %[a2], off sc1\n\t"
                    "global_load_dwordx4 %[w3], %[a3], off sc1\n\t"
                    "s_waitcnt vmcnt(0)"
                    : [w0]"=v"(w0), [w1]"=v"(w1), [w2]"=v"(w2), [w3]"=v"(w3)
                    : [a0]"v"(a0), [a1]"v"(a1), [a2]"v"(a2), [a3]"v"(a3)
                    : "memory");
                u32 ok = (w0[1] == want) + (w0[3] == want) + (w1[1] == want) + (w1[3] == want)
                       + (w2[1] == want) + (w2[3] == want) + (w3[1] == want) + (w3[3] == want);
                if (ok == 8) break;
            }
#define FILL(rep, pay0, pay1) {                                                             \
            int i0 = tid * 2 + (rep) * 1024;                                                \
            int bb2 = i0 >> 8; int p = i0 & 255;                                            \
            int bo = (bb2 << 10) + ((p << 2) ^ ((bb2 & 7) << 4));                           \
            *(u32*)((char*)hls + bo) = (pay0);                                              \
            int p1 = p + 1;                                                                 \
            int bo1 = (bb2 << 10) + ((p1 << 2) ^ ((bb2 & 7) << 4));                         \
            *(u32*)((char*)hls + bo1) = (pay1); }
            FILL(0, w0[0], w0[2]) FILL(1, w1[0], w1[2]) FILL(2, w2[0], w2[2]) FILL(3, w3[0], w3[2])
#undef FILL
        }
        __syncthreads();                                    // B1: hls ready
        v4f a0a, a1a, a0b = (v4f){0, 0, 0, 0}, a1b = (v4f){0, 0, 0, 0};
#pragma unroll
        for (int r = 0; r < 4; ++r) { a0a[r] = pv[0][r] + bs0; a1a[r] = pv[1][r] + bs1; }
#pragma unroll
        for (int kt = 0; kt < 16; kt += 2) {
            int row = lane & 15;
            int cb0 = (kt * 64 + ((lane >> 4) * 16)) ^ ((row & 7) << 4);
            int cb1 = ((kt + 1) * 64 + ((lane >> 4) * 16)) ^ ((row & 7) << 4);
            v8s af0 = *(const v8s*)((const char*)hls + row * 1024 + cb0);
            v8s af1 = *(const v8s*)((const char*)hls + row * 1024 + cb1);
            a0a = __builtin_amdgcn_mfma_f32_16x16x32_bf16(af0, bf[0][kt], a0a, 0, 0, 0);
            a1a = __builtin_amdgcn_mfma_f32_16x16x32_bf16(af0, bf[1][kt], a1a, 0, 0, 0);
            a0b = __builtin_amdgcn_mfma_f32_16x16x32_bf16(af1, bf[0][kt + 1], a0b, 0, 0, 0);
            a1b = __builtin_amdgcn_mfma_f32_16x16x32_bf16(af1, bf[1][kt + 1], a1b, 0, 0, 0);
        }
#pragma unroll
        for (int r = 0; r < 4; ++r) {
            int rr = (lane >> 4) * 4 + r;
            gls[g][rr][half * 32 + (lane & 15)] = a0a[r] + a0b[r];
            gls[g][rr][half * 32 + 16 + (lane & 15)] = a1a[r] + a1b[r];
        }
        __syncthreads();                                    // B2: gls ready (protects hls reuse)
        float i0 = gls[0][b_][u_],     f0 = gls[1][b_][u_],     g0 = gls[2][b_][u_],     o0 = gls[3][b_][u_];
        float i1 = gls[0][b_][u_ + 1], f1 = gls[1][b_][u_ + 1], g1v = gls[2][b_][u_ + 1], o1 = gls[3][b_][u_ + 1];
        c0 = sigmoidf_(f0) * c0 + sigmoidf_(i0) * tanh_fast(g0);
        c1 = sigmoidf_(f1) * c1 + sigmoidf_(i1) * tanh_fast(g1v);
        float h0 = sigmoidf_(o0) * tanh_fast(c0);
        float h1 = sigmoidf_(o1) * tanh_fast(c1);
        u32 hw = (u32)f2bf(h0) | ((u32)f2bf(h1) << 16);
        // publish first (fire-and-forget tagged store), then history + P prefetch
        __hip_atomic_store(hb + (s & 1) * 4096 + b_ * 256 + j * 32 + p_,
                           (u64)hw | ((u64)(u32)s << 32),
                           __ATOMIC_RELAXED, __HIP_MEMORY_SCOPE_AGENT);
        *(u32*)(hs + (((long)(dir * 502 + tau) * 16 + b_) * 512 + j * 64 + u_)) = hw;
        if (s + 1 < 502) {
            int tau2 = dir ? (500 - s) : (s + 1);
#pragma unroll
            for (int nt = 0; nt < 2; ++nt)
#pragma unroll
                for (int r = 0; r < 4; ++r)
                    pv[nt][r] = bf2f(Pd[(long)(tau2 * 16 + ((lane >> 4) * 4 + r)) * 4096 + col0 + nt * 16]);
        }
    }
}

// ---------- final FC + sigmoid ----------
__global__ __launch_bounds__(256) void final_kernel(const u16* __restrict__ hs, const float* __restrict__ wfc,
                                                    const float* __restrict__ bfc, float* __restrict__ out) {
    int m = blockIdx.x;                    // t*16 + b
    int t = m >> 4, b = m & 15;
    int tid = threadIdx.x;
    const u16* hf = hs + ((long)t * 16 + b) * 512;
    const u16* hr = hs + ((long)(502 + t) * 16 + b) * 512;
    float part = 0.f;
#pragma unroll
    for (int rep = 0; rep < 2; ++rep) {
        int u = tid + rep * 256;
        part += bf2f(hf[u]) * wfc[u] + bf2f(hr[u]) * wfc[512 + u];
    }
#pragma unroll
    for (int off = 32; off; off >>= 1) part += __shfl_down(part, off, 64);
    __shared__ float red[4];
    if ((tid & 63) == 0) red[tid >> 6] = part;
    __syncthreads();
    if (tid == 0) {
        float lg = red[0] + red[1] + red[2] + red[3] + bfc[0];
        out[(long)b * 502 + t] = 1.f / (1.f + __expf(-lg));
    }
}

// ---------- launch ----------
extern "C" void kernel_launch(void* const* d_in, const int* in_sizes, int n_in,
                              void* d_out, int out_size, void* d_ws, size_t ws_size,
                              hipStream_t stream) {
    const float* x     = (const float*)d_in[0];
    const float* wb    = (const float*)d_in[1];
    const float* bb    = (const float*)d_in[2];
    const float* wa    = (const float*)d_in[3];
    const float* ba    = (const float*)d_in[4];
    const float* wr    = (const float*)d_in[5];
    const float* br    = (const float*)d_in[6];
    const float* wih_f = (const float*)d_in[7];
    const float* whh_f = (const float*)d_in[8];
    const float* bih_f = (const float*)d_in[9];
    const float* bhh_f = (const float*)d_in[10];
    const float* wih_r = (const float*)d_in[11];
    const float* whh_r = (const float*)d_in[12];
    const float* bih_r = (const float*)d_in[13];
    const float* bhh_r = (const float*)d_in[14];
    const float* wfc   = (const float*)d_in[15];
    const float* bfc   = (const float*)d_in[16];
    float* out = (float*)d_out;

    char* ws = (char*)d_ws;
    // Region 1: xbf | W1 | W2 -> dead after conv GEMMs, reused for Pb
    u16* xbf = (u16*)ws;
    u16* W1  = (u16*)(ws + 33554432);
    u16* W2  = (u16*)(ws + 54525952);
    u16* Pb  = (u16*)ws;
    // Region 2: G1 | G2 -> dead after combine, reused for hs
    char* r2 = ws + 75497472;
    float* G1 = (float*)r2;
    float* G2 = (float*)(r2 + 32899072);
    u16*  hs  = (u16*)r2;
    // Region 3: persistent smalls
    char* r3 = r2 + 65798144;
    u16*  seqp = (u16*)r3;                    //  9,252,864
    u16*  wihp = (u16*)(r3 + 9252864);        //  4,718,592
    u16*  whhb = (u16*)(r3 + 13971456);       //  4,194,304
    float* bsum= (float*)(r3 + 18165760);     //     16,384
    u64*  hbuf = (u64*)(r3 + 18182144);       //    131,072 (2 dir x 2 slot x 4096 x 8B)

    // prep
    xbf_kernel<<<16384, 256, 0, stream>>>(x, xbf, 16 * 512 * 2048);
    packw_kernel<<<20480, 256, 0, stream>>>(wb, wa, wr, W1, W2);
    packwih_kernel<<<9216, 256, 0, stream>>>(wih_f, wih_r, wihp);
    packwhh_kernel<<<8192, 256, 0, stream>>>(whh_f, whh_r, whhb);
    misc_kernel<<<80, 256, 0, stream>>>(bih_f, bhh_f, bih_r, bhh_r, bsum, hbuf);

    // conv GEMMs (two launches: per-launch B panel fits per-XCD L2)
    gemm_bf16<0><<<63 * 8, 256, 0, stream>>>(xbf, W1, G1, 8032, 1024, 10240, 1024,
                                             502, 512u * 2048u, 2048u, 0u);
    gemm_bf16<0><<<63 * 8, 256, 0, stream>>>(xbf, W2, G2, 8032, 1024, 10240, 1024,
                                             502, 512u * 2048u, 2048u, 5u * 2048u);
    // seq build
    combine_kernel<<<8032, 256, 0, stream>>>(G1, G2, bb, ba, br, seqp);
    // input projections: M=8032 (t*16+b), K=576, N=4096 -> bf16 P (grid 2016 = 8*252)
    gemm_bf16<1><<<63 * 32, 256, 0, stream>>>(seqp, wihp, Pb, 8032, 4096, 576, 4096,
                                              8032, 0u, 576u, 0u);
    // recurrence: 16 WGs x 512 threads (8 WGs/dir), tagged-word protocol
    lstm_kernel<<<16, 512, 0, stream>>>(Pb, whhb, bsum, hbuf, hs);
    // output
    final_kernel<<<8032, 256, 0, stream>>>(hs, wfc, bfc, out);
}

// Round 13
// 1861.796 us; speedup vs baseline: 1.0149x; 1.0149x over previous
//
#include <hip/hip_runtime.h>
#include <hip/hip_bf16.h>

typedef short v8s __attribute__((ext_vector_type(8)));
typedef float v4f __attribute__((ext_vector_type(4)));
typedef unsigned int u32;
typedef unsigned int u32x4 __attribute__((ext_vector_type(4)));
typedef unsigned short u16;
typedef unsigned long long u64;

// ---------- helpers ----------
__device__ __forceinline__ u16 f2bf(float f) {
    union { float f; u32 u; } x; x.f = f;
    u32 r = x.u + 0x7fffu + ((x.u >> 16) & 1u);   // RNE
    return (u16)(r >> 16);
}
__device__ __forceinline__ float bf2f(u16 s) {
    union { u32 u; float f; } x; x.u = ((u32)s) << 16;
    return x.f;
}
__device__ __forceinline__ float sigmoidf_(float x) { return 1.f / (1.f + __expf(-x)); }
__device__ __forceinline__ float tanh_fast(float x) {
    float t = fminf(fmaxf(x, -15.f), 15.f);
    float e = __expf(2.f * t);
    return (e - 1.f) / (e + 1.f);
}

// ---------- prep kernels ----------
__global__ __launch_bounds__(256) void xbf_kernel(const float* __restrict__ x, u16* __restrict__ xbf, int n) {
    int i = (blockIdx.x * 256 + threadIdx.x) * 4;
    if (i + 3 < n) {
        float4 v = *(const float4*)(x + i);
        u16* d = xbf + i;
        d[0] = f2bf(v.x); d[1] = f2bf(v.y); d[2] = f2bf(v.z); d[3] = f2bf(v.w);
    }
}

// W1[n][tap*2048+d] = n<512 ? wb[n,d,tap] : wr[n-512,d,tap]
// W2[n][tap*2048+d] = n<512 ? wa[n,d,tap] : wr[n-512,d,tap+5]
__global__ __launch_bounds__(256) void packw_kernel(const float* __restrict__ wb, const float* __restrict__ wa,
                                                    const float* __restrict__ wr, u16* __restrict__ W1, u16* __restrict__ W2) {
    long e = ((long)blockIdx.x * 256 + threadIdx.x) * 4;    // < 2*1024*10240
    int which = e >= (1024L * 10240) ? 1 : 0;
    long rem = e - (long)which * 1024 * 10240;
    int n = (int)(rem / 10240);
    int kap = (int)(rem % 10240);
    int tap = kap >> 11, d = kap & 2047;
    u16 o[4];
    if (n < 512) {
        const float* src = which ? wa : wb;
#pragma unroll
        for (int q = 0; q < 4; ++q) o[q] = f2bf(src[(long)n * 10240 + (d + q) * 5 + tap]);
    } else {
        const float* src = wr + (long)(n - 512) * 20480 + tap + (which ? 5 : 0);
#pragma unroll
        for (int q = 0; q < 4; ++q) o[q] = f2bf(src[(d + q) * 10]);
    }
    *(u64*)((which ? W2 : W1) + rem) = *(const u64*)o;
}

// wihpad[(dir*2048+g)][k] (K padded 513->576)
__global__ __launch_bounds__(256) void packwih_kernel(const float* __restrict__ wf, const float* __restrict__ wr,
                                                      u16* __restrict__ Bp) {
    int idx = blockIdx.x * 256 + threadIdx.x;               // < 4096*576
    int n = idx / 576, kap = idx % 576;
    int dir = n >> 11, g = n & 2047;
    const float* src = dir ? wr : wf;
    float v = (kap < 513) ? src[(long)g * 513 + kap] : 0.f;
    Bp[idx] = f2bf(v);
}

__global__ __launch_bounds__(256) void packwhh_kernel(const float* __restrict__ whf, const float* __restrict__ whr,
                                                      u16* __restrict__ W) {
    int idx = blockIdx.x * 256 + threadIdx.x;               // < 2*2048*512 = 2^21
    int dir = idx >> 20;
    float v = dir ? whr[idx & 1048575] : whf[idx];
    W[idx] = f2bf(v);
}

// bsum + hbuf tag clear (must run every launch: graph replays reuse hbuf)
__global__ __launch_bounds__(256) void misc_kernel(const float* __restrict__ bihf, const float* __restrict__ bhhf,
                                                   const float* __restrict__ bihr, const float* __restrict__ bhhr,
                                                   float* __restrict__ bsum, u64* __restrict__ hbuf) {
    int i = blockIdx.x * 256 + threadIdx.x;                 // grid covers 4096 + 16384
    if (i < 2048) bsum[i] = bihf[i] + bhhf[i];
    else if (i < 4096) bsum[i] = bihr[i - 2048] + bhhr[i - 2048];
    else if (i < 4096 + 16384) hbuf[i - 4096] = 0xFFFFFFFF00000000ULL;
}

// ---------- bf16 GEMM: C(MxN) = A(MxK,bf16; strided rows) * B(NxK,bf16)^T ----------
// row offset (elements) of logical row m: (m/row_div)*row_mul1 + (m%row_div)*row_mul2 + row_base
// grid divisible by 8 (bijective XCD swizzle).
template <int OUTBF>
__global__ __launch_bounds__(256) void gemm_bf16(const u16* __restrict__ A, const u16* __restrict__ B,
                                                 void* __restrict__ Cv, int M, int N, int K, int ldc,
                                                 int row_div, u32 row_mul1, u32 row_mul2, u32 row_base) {
    __shared__ u16 ldsA[128 * 64];
    __shared__ u16 ldsB[128 * 64];
    const int ntn = N >> 7;
    const int nwg = gridDim.x;
    const int bid = blockIdx.x;
    const int swz = (bid & 7) * (nwg >> 3) + (bid >> 3);
    const int tm = swz / ntn, tn = swz % ntn;
    const int tid = threadIdx.x, lane = tid & 63, wv = tid >> 6;
    const int wm = wv >> 1, wn = wv & 1;
    const int qbase = wv * 4;

    u32 asrc[4], bsrc[4];
#pragma unroll
    for (int it = 0; it < 4; ++it) {
        int q = qbase + it;
        int r = q * 8 + (lane >> 3);
        int cb = ((lane & 7) * 16) ^ ((r & 7) << 4);
        int m = tm * 128 + r; if (m > M - 1) m = M - 1;
        asrc[it] = row_base + (u32)(m / row_div) * row_mul1 + (u32)(m % row_div) * row_mul2 + (u32)(cb >> 1);
        int n = tn * 128 + r;
        bsrc[it] = (u32)n * (u32)K + (u32)(cb >> 1);
    }

    v4f acc[4][4];
#pragma unroll
    for (int i = 0; i < 4; ++i)
#pragma unroll
        for (int j = 0; j < 4; ++j) acc[i][j] = (v4f){0.f, 0.f, 0.f, 0.f};

    const int KT = K >> 6;
    for (int kt = 0; kt < KT; ++kt) {
        const int k0 = kt << 6;
#pragma unroll
        for (int it = 0; it < 4; ++it) {
            int q = qbase + it;
            __builtin_amdgcn_global_load_lds(
                (const __attribute__((address_space(1))) u32*)(A + asrc[it] + k0),
                (__attribute__((address_space(3))) u32*)((char*)ldsA + q * 1024), 16, 0, 0);
            __builtin_amdgcn_global_load_lds(
                (const __attribute__((address_space(1))) u32*)(B + bsrc[it] + k0),
                (__attribute__((address_space(3))) u32*)((char*)ldsB + q * 1024), 16, 0, 0);
        }
        __syncthreads();
#pragma unroll
        for (int kk = 0; kk < 2; ++kk) {
            v8s af[4], bfr[4];
#pragma unroll
            for (int i = 0; i < 4; ++i) {
                int row = wm * 64 + i * 16 + (lane & 15);
                int cbyte = (kk * 64 + ((lane >> 4) * 16)) ^ ((row & 7) << 4);
                af[i] = *(const v8s*)((const char*)ldsA + row * 128 + cbyte);
                int rn = wn * 64 + i * 16 + (lane & 15);
                int cbn = (kk * 64 + ((lane >> 4) * 16)) ^ ((rn & 7) << 4);
                bfr[i] = *(const v8s*)((const char*)ldsB + rn * 128 + cbn);
            }
#pragma unroll
            for (int i = 0; i < 4; ++i)
#pragma unroll
                for (int j = 0; j < 4; ++j)
                    acc[i][j] = __builtin_amdgcn_mfma_f32_16x16x32_bf16(af[i], bfr[j], acc[i][j], 0, 0, 0);
        }
        __syncthreads();
    }
#pragma unroll
    for (int i = 0; i < 4; ++i)
#pragma unroll
        for (int j = 0; j < 4; ++j)
#pragma unroll
            for (int r = 0; r < 4; ++r) {
                int m = tm * 128 + wm * 64 + i * 16 + (lane >> 4) * 4 + r;
                int n = tn * 128 + wn * 64 + j * 16 + (lane & 15);
                if (m < M) {
                    if (OUTBF) ((u16*)Cv)[(long)m * ldc + n] = f2bf(acc[i][j][r]);
                    else       ((float*)Cv)[(long)m * ldc + n] = acc[i][j][r];
                }
            }
}

// ---------- combine: build seq (bf16, padded K=576, row = t*16+b) ----------
__global__ __launch_bounds__(256) void combine_kernel(const float* __restrict__ G1, const float* __restrict__ G2,
                                                      const float* __restrict__ bb, const float* __restrict__ ba,
                                                      const float* __restrict__ br, u16* __restrict__ seqpad) {
    int m = blockIdx.x;                    // b*502 + t
    int b = m / 502, t = m % 502;
    int tid = threadIdx.x;
    const float* g1 = G1 + (long)m * 1024;
    const float* g2 = G2 + (long)m * 1024;
    u16* dst = seqpad + (long)(t * 16 + b) * 576;
    float part = 0.f;
#pragma unroll
    for (int rep = 0; rep < 2; ++rep) {
        int u = tid + rep * 256;
        float db = g1[u] + bb[u];
        float da = g2[u] + ba[u];
        part += db * da;
        float vr = g1[512 + u] + g2[512 + u] + br[u];
        dst[u] = f2bf(vr);
    }
#pragma unroll
    for (int off = 32; off; off >>= 1) part += __shfl_down(part, off, 64);
    __shared__ float red[4];
    if ((tid & 63) == 0) red[tid >> 6] = part;
    __syncthreads();
    if (tid == 0) dst[512] = f2bf(red[0] + red[1] + red[2] + red[3]);
    if (tid >= 1 && tid < 64) dst[512 + tid] = 0;
}

// ---------- persistent bidirectional LSTM (R11 config + sentinel poll) ----------
// 32 WGs: dir = wg>>4, unit slice j = wg&15. 4 waves = 4 gate types, 2 n-tiles/wave.
// Tagged-u64 protocol. Detect via SENTINEL: poll only rep-0 dwordx4 (2 tags, 4KB/WG/round,
// 8x cheaper rounds); then fetch reps 1-7 once and VERIFY their 14 tags (refetch if stale —
// producers' stores are unordered across batches, verify-retry preserves correctness).
__global__ __launch_bounds__(256, 1) void lstm_kernel(const u16* __restrict__ P, const u16* __restrict__ whhbf,
                                                      const float* __restrict__ bsum, u64* hbuf,
                                                      u16* __restrict__ hs) {
    const int wg = blockIdx.x;
    const int dir = wg >> 4, j = wg & 15;
    const int tid = threadIdx.x, lane = tid & 63, w = tid >> 6;
    __shared__ u16 hls[16 * 512];          // h (batch x 512) bf16, XOR-swizzled rows
    __shared__ float gls[4][16][32];       // gate type x batch x unit

    v8s bf[2][16];                          // whh^T fragments resident all 502 steps
    const u16* whd = whhbf + (long)dir * 2048 * 512;
#pragma unroll
    for (int nt = 0; nt < 2; ++nt) {
        int n = w * 512 + j * 32 + nt * 16 + (lane & 15);
#pragma unroll
        for (int kt = 0; kt < 16; ++kt)
            bf[nt][kt] = *(const v8s*)(whd + (long)n * 512 + kt * 32 + ((lane >> 4) * 8));
    }

    for (int i = tid; i < 8192; i += 256) hls[i] = 0;

    const int b_ = tid >> 4;
    const int u_ = (tid * 2) & 31;
    float c0 = 0.f, c1 = 0.f;
    u64* hb = hbuf + dir * 2 * 4096;
    const int col0 = w * 512 + j * 32 + (lane & 15);
    const float bs0 = bsum[dir * 2048 + col0];
    const float bs1 = bsum[dir * 2048 + col0 + 16];
    const u16* Pd = P + dir * 2048;

    // prefetch P for s=0
    float pv[2][4];
    {
        int tau = dir ? 501 : 0;
#pragma unroll
        for (int nt = 0; nt < 2; ++nt)
#pragma unroll
            for (int r = 0; r < 4; ++r)
                pv[nt][r] = bf2f(Pd[(long)(tau * 16 + ((lane >> 4) * 4 + r)) * 4096 + col0 + nt * 16]);
    }
    __syncthreads();

    for (int s = 0; s < 502; ++s) {
        const int tau = dir ? (501 - s) : s;
        if (s > 0) {
            const u64* slotp = hb + ((s - 1) & 1) * 4096;
            const u32 want = (u32)(s - 1);
            u64 base = (u64)slotp + (u64)tid * 16;           // thread owns words tid*2 + rep*512 (+0/1)
            u64 a0 = base,          a1 = base + 4096,  a2 = base + 8192,  a3 = base + 12288;
            u64 a4 = base + 16384,  a5 = base + 20480, a6 = base + 24576, a7 = base + 28672;
            u32x4 w0, w1, w2, w3, w4, w5, w6, w7;
            // ---- sentinel poll: rep 0 only (4KB/WG per round) ----
            for (;;) {
                asm volatile(
                    "global_load_dwordx4 %[w0], %[a0], off sc1\n\t"
                    "s_waitcnt vmcnt(0)"
                    : [w0]"=v"(w0)
                    : [a0]"v"(a0)
                    : "memory");
                if (w0[1] == want && w0[3] == want) break;
            }
            // ---- bulk fetch reps 1-7 with tag verify (refetch if any stale) ----
            for (;;) {
                asm volatile(
                    "global_load_dwordx4 %[w1], %[a1], off sc1\n\t"
                    "global_load_dwordx4 %[w2], %[a2], off sc1\n\t"
                    "global_load_dwordx4 %[w3], %[a3], off sc1\n\t"
                    "global_load_dwordx4 %[w4], %[a4], off sc1\n\t"
                    "global_load_dwordx4 %[w5], %[a5], off sc1\n\t"
                    "global_load_dwordx4 %[w6], %[a6], off sc1\n\t"
                    "global_load_dwordx4 %[w7], %[a7], off sc1\n\t"
                    "s_waitcnt vmcnt(0)"
                    : [w1]"=v"(w1), [w2]"=v"(w2), [w3]"=v"(w3),
                      [w4]"=v"(w4), [w5]"=v"(w5), [w6]"=v"(w6), [w7]"=v"(w7)
                    : [a1]"v"(a1), [a2]"v"(a2), [a3]"v"(a3),
                      [a4]"v"(a4), [a5]"v"(a5), [a6]"v"(a6), [a7]"v"(a7)
                    : "memory");
                u32 ok = (w1[1] == want) + (w1[3] == want)
                       + (w2[1] == want) + (w2[3] == want) + (w3[1] == want) + (w3[3] == want)
                       + (w4[1] == want) + (w4[3] == want) + (w5[1] == want) + (w5[3] == want)
                       + (w6[1] == want) + (w6[3] == want) + (w7[1] == want) + (w7[3] == want);
                if (ok == 14) break;
            }
#define FILL(rep, pay0, pay1) {                                                             \
            int i0 = tid * 2 + (rep) * 512;                                                 \
            int bb2 = i0 >> 8; int p = i0 & 255;                                            \
            int bo = (bb2 << 10) + ((p << 2) ^ ((bb2 & 7) << 4));                           \
            *(u32*)((char*)hls + bo) = (pay0);                                              \
            int p1 = p + 1;                                                                 \
            int bo1 = (bb2 << 10) + ((p1 << 2) ^ ((bb2 & 7) << 4));                         \
            *(u32*)((char*)hls + bo1) = (pay1); }
            FILL(0, w0[0], w0[2]) FILL(1, w1[0], w1[2]) FILL(2, w2[0], w2[2]) FILL(3, w3[0], w3[2])
            FILL(4, w4[0], w4[2]) FILL(5, w5[0], w5[2]) FILL(6, w6[0], w6[2]) FILL(7, w7[0], w7[2])
#undef FILL
        }
        __syncthreads();                                    // B1: hls ready
        v4f a0a, a1a, a0b = (v4f){0, 0, 0, 0}, a1b = (v4f){0, 0, 0, 0};
#pragma unroll
        for (int r = 0; r < 4; ++r) { a0a[r] = pv[0][r] + bs0; a1a[r] = pv[1][r] + bs1; }
#pragma unroll
        for (int kt = 0; kt < 16; kt += 2) {
            int row = lane & 15;
            int cb0 = (kt * 64 + ((lane >> 4) * 16)) ^ ((row & 7) << 4);
            int cb1 = ((kt + 1) * 64 + ((lane >> 4) * 16)) ^ ((row & 7) << 4);
            v8s af0 = *(const v8s*)((const char*)hls + row * 1024 + cb0);
            v8s af1 = *(const v8s*)((const char*)hls + row * 1024 + cb1);
            a0a = __builtin_amdgcn_mfma_f32_16x16x32_bf16(af0, bf[0][kt], a0a, 0, 0, 0);
            a1a = __builtin_amdgcn_mfma_f32_16x16x32_bf16(af0, bf[1][kt], a1a, 0, 0, 0);
            a0b = __builtin_amdgcn_mfma_f32_16x16x32_bf16(af1, bf[0][kt + 1], a0b, 0, 0, 0);
            a1b = __builtin_amdgcn_mfma_f32_16x16x32_bf16(af1, bf[1][kt + 1], a1b, 0, 0, 0);
        }
#pragma unroll
        for (int r = 0; r < 4; ++r) {
            gls[w][(lane >> 4) * 4 + r][(lane & 15)] = a0a[r] + a0b[r];
            gls[w][(lane >> 4) * 4 + r][16 + (lane & 15)] = a1a[r] + a1b[r];
        }
        __syncthreads();                                    // B2: gls ready (protects hls reuse)
        float i0 = gls[0][b_][u_],     f0 = gls[1][b_][u_],     g0 = gls[2][b_][u_],     o0 = gls[3][b_][u_];
        float i1 = gls[0][b_][u_ + 1], f1 = gls[1][b_][u_ + 1], g1v = gls[2][b_][u_ + 1], o1 = gls[3][b_][u_ + 1];
        c0 = sigmoidf_(f0) * c0 + sigmoidf_(i0) * tanh_fast(g0);
        c1 = sigmoidf_(f1) * c1 + sigmoidf_(i1) * tanh_fast(g1v);
        float h0 = sigmoidf_(o0) * tanh_fast(c0);
        float h1 = sigmoidf_(o1) * tanh_fast(c1);
        u32 hw = (u32)f2bf(h0) | ((u32)f2bf(h1) << 16);
        int gi = (b_ * 512 + j * 32 + u_) >> 1;
        __hip_atomic_store(hb + (s & 1) * 4096 + gi, (u64)hw | ((u64)(u32)s << 32),
                           __ATOMIC_RELAXED, __HIP_MEMORY_SCOPE_AGENT);
        *(u32*)(hs + (((long)(dir * 502 + tau) * 16 + b_) * 512 + j * 32 + u_)) = hw;
        if (s + 1 < 502) {
            int tau2 = dir ? (500 - s) : (s + 1);
#pragma unroll
            for (int nt = 0; nt < 2; ++nt)
#pragma unroll
                for (int r = 0; r < 4; ++r)
                    pv[nt][r] = bf2f(Pd[(long)(tau2 * 16 + ((lane >> 4) * 4 + r)) * 4096 + col0 + nt * 16]);
        }
    }
}

// ---------- final FC + sigmoid ----------
__global__ __launch_bounds__(256) void final_kernel(const u16* __restrict__ hs, const float* __restrict__ wfc,
                                                    const float* __restrict__ bfc, float* __restrict__ out) {
    int m = blockIdx.x;                    // t*16 + b
    int t = m >> 4, b = m & 15;
    int tid = threadIdx.x;
    const u16* hf = hs + ((long)t * 16 + b) * 512;
    const u16* hr = hs + ((long)(502 + t) * 16 + b) * 512;
    float part = 0.f;
#pragma unroll
    for (int rep = 0; rep < 2; ++rep) {
        int u = tid + rep * 256;
        part += bf2f(hf[u]) * wfc[u] + bf2f(hr[u]) * wfc[512 + u];
    }
#pragma unroll
    for (int off = 32; off; off >>= 1) part += __shfl_down(part, off, 64);
    __shared__ float red[4];
    if ((tid & 63) == 0) red[tid >> 6] = part;
    __syncthreads();
    if (tid == 0) {
        float lg = red[0] + red[1] + red[2] + red[3] + bfc[0];
        out[(long)b * 502 + t] = 1.f / (1.f + __expf(-lg));
    }
}

// ---------- launch ----------
extern "C" void kernel_launch(void* const* d_in, const int* in_sizes, int n_in,
                              void* d_out, int out_size, void* d_ws, size_t ws_size,
                              hipStream_t stream) {
    const float* x     = (const float*)d_in[0];
    const float* wb    = (const float*)d_in[1];
    const float* bb    = (const float*)d_in[2];
    const float* wa    = (const float*)d_in[3];
    const float* ba    = (const float*)d_in[4];
    const float* wr    = (const float*)d_in[5];
    const float* br    = (const float*)d_in[6];
    const float* wih_f = (const float*)d_in[7];
    const float* whh_f = (const float*)d_in[8];
    const float* bih_f = (const float*)d_in[9];
    const float* bhh_f = (const float*)d_in[10];
    const float* wih_r = (const float*)d_in[11];
    const float* whh_r = (const float*)d_in[12];
    const float* bih_r = (const float*)d_in[13];
    const float* bhh_r = (const float*)d_in[14];
    const float* wfc   = (const float*)d_in[15];
    const float* bfc   = (const float*)d_in[16];
    float* out = (float*)d_out;

    char* ws = (char*)d_ws;
    // Region 1: xbf | W1 | W2 -> dead after conv GEMMs, reused for Pb
    u16* xbf = (u16*)ws;
    u16* W1  = (u16*)(ws + 33554432);
    u16* W2  = (u16*)(ws + 54525952);
    u16* Pb  = (u16*)ws;
    // Region 2: G1 | G2 -> dead after combine, reused for hs
    char* r2 = ws + 75497472;
    float* G1 = (float*)r2;
    float* G2 = (float*)(r2 + 32899072);
    u16*  hs  = (u16*)r2;
    // Region 3: persistent smalls
    char* r3 = r2 + 65798144;
    u16*  seqp = (u16*)r3;                    //  9,252,864
    u16*  wihp = (u16*)(r3 + 9252864);        //  4,718,592
    u16*  whhb = (u16*)(r3 + 13971456);       //  4,194,304
    float* bsum= (float*)(r3 + 18165760);     //     16,384
    u64*  hbuf = (u64*)(r3 + 18182144);       //    131,072 (2 dir x 2 slot x 4096 x 8B)

    // prep
    xbf_kernel<<<16384, 256, 0, stream>>>(x, xbf, 16 * 512 * 2048);
    packw_kernel<<<20480, 256, 0, stream>>>(wb, wa, wr, W1, W2);
    packwih_kernel<<<9216, 256, 0, stream>>>(wih_f, wih_r, wihp);
    packwhh_kernel<<<8192, 256, 0, stream>>>(whh_f, whh_r, whhb);
    misc_kernel<<<80, 256, 0, stream>>>(bih_f, bhh_f, bih_r, bhh_r, bsum, hbuf);

    // conv GEMMs (two launches: per-launch B panel fits per-XCD L2)
    gemm_bf16<0><<<63 * 8, 256, 0, stream>>>(xbf, W1, G1, 8032, 1024, 10240, 1024,
                                             502, 512u * 2048u, 2048u, 0u);
    gemm_bf16<0><<<63 * 8, 256, 0, stream>>>(xbf, W2, G2, 8032, 1024, 10240, 1024,
                                             502, 512u * 2048u, 2048u, 5u * 2048u);
    // seq build
    combine_kernel<<<8032, 256, 0, stream>>>(G1, G2, bb, ba, br, seqp);
    // input projections: M=8032 (t*16+b), K=576, N=4096 -> bf16 P (grid 2016 = 8*252)
    gemm_bf16<1><<<63 * 32, 256, 0, stream>>>(seqp, wihp, Pb, 8032, 4096, 576, 4096,
                                              8032, 0u, 576u, 0u);
    // recurrence: R11 config + sentinel poll
    lstm_kernel<<<32, 256, 0, stream>>>(Pb, whhb, bsum, hbuf, hs);
    // output
    final_kernel<<<8032, 256, 0, stream>>>(hs, wfc, bfc, out);
}

// Round 14
// 1781.641 us; speedup vs baseline: 1.0606x; 1.0450x over previous
//
#include <hip/hip_runtime.h>
#include <hip/hip_bf16.h>

typedef short v8s __attribute__((ext_vector_type(8)));
typedef float v4f __attribute__((ext_vector_type(4)));
typedef unsigned int u32;
typedef unsigned int u32x4 __attribute__((ext_vector_type(4)));
typedef unsigned short u16;
typedef unsigned long long u64;

// ---------- helpers ----------
__device__ __forceinline__ u16 f2bf(float f) {
    union { float f; u32 u; } x; x.f = f;
    u32 r = x.u + 0x7fffu + ((x.u >> 16) & 1u);   // RNE
    return (u16)(r >> 16);
}
__device__ __forceinline__ float bf2f(u16 s) {
    union { u32 u; float f; } x; x.u = ((u32)s) << 16;
    return x.f;
}
__device__ __forceinline__ float sigmoidf_(float x) { return 1.f / (1.f + __expf(-x)); }
__device__ __forceinline__ float tanh_fast(float x) {
    float t = fminf(fmaxf(x, -15.f), 15.f);
    float e = __expf(2.f * t);
    return (e - 1.f) / (e + 1.f);
}

// ---------- prep kernels ----------
__global__ __launch_bounds__(256) void xbf_kernel(const float* __restrict__ x, u16* __restrict__ xbf, int n) {
    int i = (blockIdx.x * 256 + threadIdx.x) * 4;
    if (i + 3 < n) {
        float4 v = *(const float4*)(x + i);
        u16* d = xbf + i;
        d[0] = f2bf(v.x); d[1] = f2bf(v.y); d[2] = f2bf(v.z); d[3] = f2bf(v.w);
    }
}

// W1[n][tap*2048+d] = n<512 ? wb[n,d,tap] : wr[n-512,d,tap]
// W2[n][tap*2048+d] = n<512 ? wa[n,d,tap] : wr[n-512,d,tap+5]
__global__ __launch_bounds__(256) void packw_kernel(const float* __restrict__ wb, const float* __restrict__ wa,
                                                    const float* __restrict__ wr, u16* __restrict__ W1, u16* __restrict__ W2) {
    long e = ((long)blockIdx.x * 256 + threadIdx.x) * 4;    // < 2*1024*10240
    int which = e >= (1024L * 10240) ? 1 : 0;
    long rem = e - (long)which * 1024 * 10240;
    int n = (int)(rem / 10240);
    int kap = (int)(rem % 10240);
    int tap = kap >> 11, d = kap & 2047;
    u16 o[4];
    if (n < 512) {
        const float* src = which ? wa : wb;
#pragma unroll
        for (int q = 0; q < 4; ++q) o[q] = f2bf(src[(long)n * 10240 + (d + q) * 5 + tap]);
    } else {
        const float* src = wr + (long)(n - 512) * 20480 + tap + (which ? 5 : 0);
#pragma unroll
        for (int q = 0; q < 4; ++q) o[q] = f2bf(src[(d + q) * 10]);
    }
    *(u64*)((which ? W2 : W1) + rem) = *(const u64*)o;
}

// wihpad[(dir*2048+g)][k] (K padded 513->576)
__global__ __launch_bounds__(256) void packwih_kernel(const float* __restrict__ wf, const float* __restrict__ wr,
                                                      u16* __restrict__ Bp) {
    int idx = blockIdx.x * 256 + threadIdx.x;               // < 4096*576
    int n = idx / 576, kap = idx % 576;
    int dir = n >> 11, g = n & 2047;
    const float* src = dir ? wr : wf;
    float v = (kap < 513) ? src[(long)g * 513 + kap] : 0.f;
    Bp[idx] = f2bf(v);
}

__global__ __launch_bounds__(256) void packwhh_kernel(const float* __restrict__ whf, const float* __restrict__ whr,
                                                      u16* __restrict__ W) {
    int idx = blockIdx.x * 256 + threadIdx.x;               // < 2*2048*512 = 2^21
    int dir = idx >> 20;
    float v = dir ? whr[idx & 1048575] : whf[idx];
    W[idx] = f2bf(v);
}

// bsum only (hbuf init moved to hbinit_kernel, launched after proj GEMM)
__global__ __launch_bounds__(256) void misc_kernel(const float* __restrict__ bihf, const float* __restrict__ bhhf,
                                                   const float* __restrict__ bihr, const float* __restrict__ bhhr,
                                                   float* __restrict__ bsum) {
    int i = blockIdx.x * 256 + threadIdx.x;                 // grid covers 4096
    if (i < 2048) bsum[i] = bihf[i] + bhhf[i];
    else if (i < 4096) bsum[i] = bihr[i - 2048] + bhhr[i - 2048];
}

// clear tags in all 4 publication copies (runs AFTER proj GEMM: lives in dead G region)
__global__ __launch_bounds__(256) void hbinit_kernel(u64* __restrict__ hbig) {
    int i = blockIdx.x * 256 + threadIdx.x;                 // < 4*2*2*4096 = 65536
    hbig[i] = 0xFFFFFFFF00000000ULL;
}

// ---------- bf16 GEMM: C(MxN) = A(MxK,bf16; strided rows) * B(NxK,bf16)^T ----------
// row offset (elements) of logical row m: (m/row_div)*row_mul1 + (m%row_div)*row_mul2 + row_base
// grid divisible by 8 (bijective XCD swizzle).
template <int OUTBF>
__global__ __launch_bounds__(256) void gemm_bf16(const u16* __restrict__ A, const u16* __restrict__ B,
                                                 void* __restrict__ Cv, int M, int N, int K, int ldc,
                                                 int row_div, u32 row_mul1, u32 row_mul2, u32 row_base) {
    __shared__ u16 ldsA[128 * 64];
    __shared__ u16 ldsB[128 * 64];
    const int ntn = N >> 7;
    const int nwg = gridDim.x;
    const int bid = blockIdx.x;
    const int swz = (bid & 7) * (nwg >> 3) + (bid >> 3);
    const int tm = swz / ntn, tn = swz % ntn;
    const int tid = threadIdx.x, lane = tid & 63, wv = tid >> 6;
    const int wm = wv >> 1, wn = wv & 1;
    const int qbase = wv * 4;

    u32 asrc[4], bsrc[4];
#pragma unroll
    for (int it = 0; it < 4; ++it) {
        int q = qbase + it;
        int r = q * 8 + (lane >> 3);
        int cb = ((lane & 7) * 16) ^ ((r & 7) << 4);
        int m = tm * 128 + r; if (m > M - 1) m = M - 1;
        asrc[it] = row_base + (u32)(m / row_div) * row_mul1 + (u32)(m % row_div) * row_mul2 + (u32)(cb >> 1);
        int n = tn * 128 + r;
        bsrc[it] = (u32)n * (u32)K + (u32)(cb >> 1);
    }

    v4f acc[4][4];
#pragma unroll
    for (int i = 0; i < 4; ++i)
#pragma unroll
        for (int j = 0; j < 4; ++j) acc[i][j] = (v4f){0.f, 0.f, 0.f, 0.f};

    const int KT = K >> 6;
    for (int kt = 0; kt < KT; ++kt) {
        const int k0 = kt << 6;
#pragma unroll
        for (int it = 0; it < 4; ++it) {
            int q = qbase + it;
            __builtin_amdgcn_global_load_lds(
                (const __attribute__((address_space(1))) u32*)(A + asrc[it] + k0),
                (__attribute__((address_space(3))) u32*)((char*)ldsA + q * 1024), 16, 0, 0);
            __builtin_amdgcn_global_load_lds(
                (const __attribute__((address_space(1))) u32*)(B + bsrc[it] + k0),
                (__attribute__((address_space(3))) u32*)((char*)ldsB + q * 1024), 16, 0, 0);
        }
        __syncthreads();
#pragma unroll
        for (int kk = 0; kk < 2; ++kk) {
            v8s af[4], bfr[4];
#pragma unroll
            for (int i = 0; i < 4; ++i) {
                int row = wm * 64 + i * 16 + (lane & 15);
                int cbyte = (kk * 64 + ((lane >> 4) * 16)) ^ ((row & 7) << 4);
                af[i] = *(const v8s*)((const char*)ldsA + row * 128 + cbyte);
                int rn = wn * 64 + i * 16 + (lane & 15);
                int cbn = (kk * 64 + ((lane >> 4) * 16)) ^ ((rn & 7) << 4);
                bfr[i] = *(const v8s*)((const char*)ldsB + rn * 128 + cbn);
            }
#pragma unroll
            for (int i = 0; i < 4; ++i)
#pragma unroll
                for (int j = 0; j < 4; ++j)
                    acc[i][j] = __builtin_amdgcn_mfma_f32_16x16x32_bf16(af[i], bfr[j], acc[i][j], 0, 0, 0);
        }
        __syncthreads();
    }
#pragma unroll
    for (int i = 0; i < 4; ++i)
#pragma unroll
        for (int j = 0; j < 4; ++j)
#pragma unroll
            for (int r = 0; r < 4; ++r) {
                int m = tm * 128 + wm * 64 + i * 16 + (lane >> 4) * 4 + r;
                int n = tn * 128 + wn * 64 + j * 16 + (lane & 15);
                if (m < M) {
                    if (OUTBF) ((u16*)Cv)[(long)m * ldc + n] = f2bf(acc[i][j][r]);
                    else       ((float*)Cv)[(long)m * ldc + n] = acc[i][j][r];
                }
            }
}

// ---------- combine: build seq (bf16, padded K=576, row = t*16+b) ----------
__global__ __launch_bounds__(256) void combine_kernel(const float* __restrict__ G1, const float* __restrict__ G2,
                                                      const float* __restrict__ bb, const float* __restrict__ ba,
                                                      const float* __restrict__ br, u16* __restrict__ seqpad) {
    int m = blockIdx.x;                    // b*502 + t
    int b = m / 502, t = m % 502;
    int tid = threadIdx.x;
    const float* g1 = G1 + (long)m * 1024;
    const float* g2 = G2 + (long)m * 1024;
    u16* dst = seqpad + (long)(t * 16 + b) * 576;
    float part = 0.f;
#pragma unroll
    for (int rep = 0; rep < 2; ++rep) {
        int u = tid + rep * 256;
        float db = g1[u] + bb[u];
        float da = g2[u] + ba[u];
        part += db * da;
        float vr = g1[512 + u] + g2[512 + u] + br[u];
        dst[u] = f2bf(vr);
    }
#pragma unroll
    for (int off = 32; off; off >>= 1) part += __shfl_down(part, off, 64);
    __shared__ float red[4];
    if ((tid & 63) == 0) red[tid >> 6] = part;
    __syncthreads();
    if (tid == 0) dst[512] = f2bf(red[0] + red[1] + red[2] + red[3]);
    if (tid >= 1 && tid < 64) dst[512 + tid] = 0;
}

// ---------- persistent bidirectional LSTM (R11 config + 4-copy publish spread) ----------
// 32 WGs: dir = wg>>4, unit slice j = wg&15. 4 waves = 4 gate types, 2 n-tiles/wave.
// Tagged-u64 protocol, dwordx4 sc1 polls (R11-proven). NEW: producers publish each tagged
// word to 4 copies (128KB stride); consumer WG polls only copy wg&3 -> 4x fewer consumers
// per hot address set (contention probe; consumer structure unchanged).
__global__ __launch_bounds__(256, 1) void lstm_kernel(const u16* __restrict__ P, const u16* __restrict__ whhbf,
                                                      const float* __restrict__ bsum, u64* hbig,
                                                      u16* __restrict__ hs) {
    const int wg = blockIdx.x;
    const int dir = wg >> 4, j = wg & 15;
    const int copy = wg & 3;
    const int tid = threadIdx.x, lane = tid & 63, w = tid >> 6;
    __shared__ u16 hls[16 * 512];          // h (batch x 512) bf16, XOR-swizzled rows
    __shared__ float gls[4][16][32];       // gate type x batch x unit

    v8s bf[2][16];                          // whh^T fragments resident all 502 steps
    const u16* whd = whhbf + (long)dir * 2048 * 512;
#pragma unroll
    for (int nt = 0; nt < 2; ++nt) {
        int n = w * 512 + j * 32 + nt * 16 + (lane & 15);
#pragma unroll
        for (int kt = 0; kt < 16; ++kt)
            bf[nt][kt] = *(const v8s*)(whd + (long)n * 512 + kt * 32 + ((lane >> 4) * 8));
    }

    for (int i = tid; i < 8192; i += 256) hls[i] = 0;

    const int b_ = tid >> 4;
    const int u_ = (tid * 2) & 31;
    float c0 = 0.f, c1 = 0.f;
    // copy c lives at hbig + c*16384; within a copy: dir*8192 + slot*4096
    u64* myread = hbig + (long)copy * 16384 + dir * 8192;
    const int col0 = w * 512 + j * 32 + (lane & 15);
    const float bs0 = bsum[dir * 2048 + col0];
    const float bs1 = bsum[dir * 2048 + col0 + 16];
    const u16* Pd = P + dir * 2048;

    // prefetch P for s=0
    float pv[2][4];
    {
        int tau = dir ? 501 : 0;
#pragma unroll
        for (int nt = 0; nt < 2; ++nt)
#pragma unroll
            for (int r = 0; r < 4; ++r)
                pv[nt][r] = bf2f(Pd[(long)(tau * 16 + ((lane >> 4) * 4 + r)) * 4096 + col0 + nt * 16]);
    }
    __syncthreads();

    for (int s = 0; s < 502; ++s) {
        const int tau = dir ? (501 - s) : s;
        if (s > 0) {
            const u64* slotp = myread + ((s - 1) & 1) * 4096;
            const u32 want = (u32)(s - 1);
            u64 base = (u64)slotp + (u64)tid * 16;           // thread reads words tid*2 + rep*512 (+0/1)
            u64 a0 = base,          a1 = base + 4096,  a2 = base + 8192,  a3 = base + 12288;
            u64 a4 = base + 16384,  a5 = base + 20480, a6 = base + 24576, a7 = base + 28672;
            u32x4 w0, w1, w2, w3, w4, w5, w6, w7;
            for (;;) {
                asm volatile(
                    "global_load_dwordx4 %[w0], %[a0], off sc1\n\t"
                    "global_load_dwordx4 %[w1], %[a1], off sc1\n\t"
                    "global_load_dwordx4 %[w2], %[a2], off sc1\n\t"
                    "global_load_dwordx4 %[w3], %[a3], off sc1\n\t"
                    "global_load_dwordx4 %[w4], %[a4], off sc1\n\t"
                    "global_load_dwordx4 %[w5], %[a5], off sc1\n\t"
                    "global_load_dwordx4 %[w6], %[a6], off sc1\n\t"
                    "global_load_dwordx4 %[w7], %[a7], off sc1\n\t"
                    "s_waitcnt vmcnt(0)"
                    : [w0]"=v"(w0), [w1]"=v"(w1), [w2]"=v"(w2), [w3]"=v"(w3),
                      [w4]"=v"(w4), [w5]"=v"(w5), [w6]"=v"(w6), [w7]"=v"(w7)
                    : [a0]"v"(a0), [a1]"v"(a1), [a2]"v"(a2), [a3]"v"(a3),
                      [a4]"v"(a4), [a5]"v"(a5), [a6]"v"(a6), [a7]"v"(a7)
                    : "memory");
                u32 ok = (w0[1] == want) + (w0[3] == want) + (w1[1] == want) + (w1[3] == want)
                       + (w2[1] == want) + (w2[3] == want) + (w3[1] == want) + (w3[3] == want)
                       + (w4[1] == want) + (w4[3] == want) + (w5[1] == want) + (w5[3] == want)
                       + (w6[1] == want) + (w6[3] == want) + (w7[1] == want) + (w7[3] == want);
                if (ok == 16) break;
            }
#define FILL(rep, pay0, pay1) {                                                             \
            int i0 = tid * 2 + (rep) * 512;                                                 \
            int bb2 = i0 >> 8; int p = i0 & 255;                                            \
            int bo = (bb2 << 10) + ((p << 2) ^ ((bb2 & 7) << 4));                           \
            *(u32*)((char*)hls + bo) = (pay0);                                              \
            int p1 = p + 1;                                                                 \
            int bo1 = (bb2 << 10) + ((p1 << 2) ^ ((bb2 & 7) << 4));                         \
            *(u32*)((char*)hls + bo1) = (pay1); }
            FILL(0, w0[0], w0[2]) FILL(1, w1[0], w1[2]) FILL(2, w2[0], w2[2]) FILL(3, w3[0], w3[2])
            FILL(4, w4[0], w4[2]) FILL(5, w5[0], w5[2]) FILL(6, w6[0], w6[2]) FILL(7, w7[0], w7[2])
#undef FILL
        }
        __syncthreads();                                    // B1: hls ready
        v4f a0a, a1a, a0b = (v4f){0, 0, 0, 0}, a1b = (v4f){0, 0, 0, 0};
#pragma unroll
        for (int r = 0; r < 4; ++r) { a0a[r] = pv[0][r] + bs0; a1a[r] = pv[1][r] + bs1; }
#pragma unroll
        for (int kt = 0; kt < 16; kt += 2) {
            int row = lane & 15;
            int cb0 = (kt * 64 + ((lane >> 4) * 16)) ^ ((row & 7) << 4);
            int cb1 = ((kt + 1) * 64 + ((lane >> 4) * 16)) ^ ((row & 7) << 4);
            v8s af0 = *(const v8s*)((const char*)hls + row * 1024 + cb0);
            v8s af1 = *(const v8s*)((const char*)hls + row * 1024 + cb1);
            a0a = __builtin_amdgcn_mfma_f32_16x16x32_bf16(af0, bf[0][kt], a0a, 0, 0, 0);
            a1a = __builtin_amdgcn_mfma_f32_16x16x32_bf16(af0, bf[1][kt], a1a, 0, 0, 0);
            a0b = __builtin_amdgcn_mfma_f32_16x16x32_bf16(af1, bf[0][kt + 1], a0b, 0, 0, 0);
            a1b = __builtin_amdgcn_mfma_f32_16x16x32_bf16(af1, bf[1][kt + 1], a1b, 0, 0, 0);
        }
#pragma unroll
        for (int r = 0; r < 4; ++r) {
            gls[w][(lane >> 4) * 4 + r][(lane & 15)] = a0a[r] + a0b[r];
            gls[w][(lane >> 4) * 4 + r][16 + (lane & 15)] = a1a[r] + a1b[r];
        }
        __syncthreads();                                    // B2: gls ready (protects hls reuse)
        float i0 = gls[0][b_][u_],     f0 = gls[1][b_][u_],     g0 = gls[2][b_][u_],     o0 = gls[3][b_][u_];
        float i1 = gls[0][b_][u_ + 1], f1 = gls[1][b_][u_ + 1], g1v = gls[2][b_][u_ + 1], o1 = gls[3][b_][u_ + 1];
        c0 = sigmoidf_(f0) * c0 + sigmoidf_(i0) * tanh_fast(g0);
        c1 = sigmoidf_(f1) * c1 + sigmoidf_(i1) * tanh_fast(g1v);
        float h0 = sigmoidf_(o0) * tanh_fast(c0);
        float h1 = sigmoidf_(o1) * tanh_fast(c1);
        u32 hw = (u32)f2bf(h0) | ((u32)f2bf(h1) << 16);
        int gi = (b_ * 512 + j * 32 + u_) >> 1;
        u64 word = (u64)hw | ((u64)(u32)s << 32);
        long off = (long)dir * 8192 + (s & 1) * 4096 + gi;
#pragma unroll
        for (int cpy = 0; cpy < 4; ++cpy)
            __hip_atomic_store(hbig + (long)cpy * 16384 + off, word,
                               __ATOMIC_RELAXED, __HIP_MEMORY_SCOPE_AGENT);
        *(u32*)(hs + (((long)(dir * 502 + tau) * 16 + b_) * 512 + j * 32 + u_)) = hw;
        if (s + 1 < 502) {
            int tau2 = dir ? (500 - s) : (s + 1);
#pragma unroll
            for (int nt = 0; nt < 2; ++nt)
#pragma unroll
                for (int r = 0; r < 4; ++r)
                    pv[nt][r] = bf2f(Pd[(long)(tau2 * 16 + ((lane >> 4) * 4 + r)) * 4096 + col0 + nt * 16]);
        }
    }
}

// ---------- final FC + sigmoid ----------
__global__ __launch_bounds__(256) void final_kernel(const u16* __restrict__ hs, const float* __restrict__ wfc,
                                                    const float* __restrict__ bfc, float* __restrict__ out) {
    int m = blockIdx.x;                    // t*16 + b
    int t = m >> 4, b = m & 15;
    int tid = threadIdx.x;
    const u16* hf = hs + ((long)t * 16 + b) * 512;
    const u16* hr = hs + ((long)(502 + t) * 16 + b) * 512;
    float part = 0.f;
#pragma unroll
    for (int rep = 0; rep < 2; ++rep) {
        int u = tid + rep * 256;
        part += bf2f(hf[u]) * wfc[u] + bf2f(hr[u]) * wfc[512 + u];
    }
#pragma unroll
    for (int off = 32; off; off >>= 1) part += __shfl_down(part, off, 64);
    __shared__ float red[4];
    if ((tid & 63) == 0) red[tid >> 6] = part;
    __syncthreads();
    if (tid == 0) {
        float lg = red[0] + red[1] + red[2] + red[3] + bfc[0];
        out[(long)b * 502 + t] = 1.f / (1.f + __expf(-lg));
    }
}

// ---------- launch ----------
extern "C" void kernel_launch(void* const* d_in, const int* in_sizes, int n_in,
                              void* d_out, int out_size, void* d_ws, size_t ws_size,
                              hipStream_t stream) {
    const float* x     = (const float*)d_in[0];
    const float* wb    = (const float*)d_in[1];
    const float* bb    = (const float*)d_in[2];
    const float* wa    = (const float*)d_in[3];
    const float* ba    = (const float*)d_in[4];
    const float* wr    = (const float*)d_in[5];
    const float* br    = (const float*)d_in[6];
    const float* wih_f = (const float*)d_in[7];
    const float* whh_f = (const float*)d_in[8];
    const float* bih_f = (const float*)d_in[9];
    const float* bhh_f = (const float*)d_in[10];
    const float* wih_r = (const float*)d_in[11];
    const float* whh_r = (const float*)d_in[12];
    const float* bih_r = (const float*)d_in[13];
    const float* bhh_r = (const float*)d_in[14];
    const float* wfc   = (const float*)d_in[15];
    const float* bfc   = (const float*)d_in[16];
    float* out = (float*)d_out;

    char* ws = (char*)d_ws;
    // Region 1: xbf | W1 | W2 -> dead after conv GEMMs, reused for Pb
    u16* xbf = (u16*)ws;
    u16* W1  = (u16*)(ws + 33554432);
    u16* W2  = (u16*)(ws + 54525952);
    u16* Pb  = (u16*)ws;
    // Region 2: G1 | G2 -> dead after combine, reused for hs (16.45 MB) and,
    // during lstm only, the 4-copy publication buffer at +20 MB (inits after proj GEMM).
    char* r2 = ws + 75497472;
    float* G1 = (float*)r2;
    float* G2 = (float*)(r2 + 32899072);
    u16*  hs  = (u16*)r2;
    u64*  hbig= (u64*)(r2 + 20971520);        // 4 copies x 2 dir x 2 slot x 4096 x 8B = 512 KB
    // Region 3: persistent smalls
    char* r3 = r2 + 65798144;
    u16*  seqp = (u16*)r3;                    //  9,252,864
    u16*  wihp = (u16*)(r3 + 9252864);        //  4,718,592
    u16*  whhb = (u16*)(r3 + 13971456);       //  4,194,304
    float* bsum= (float*)(r3 + 18165760);     //     16,384

    // prep
    xbf_kernel<<<16384, 256, 0, stream>>>(x, xbf, 16 * 512 * 2048);
    packw_kernel<<<20480, 256, 0, stream>>>(wb, wa, wr, W1, W2);
    packwih_kernel<<<9216, 256, 0, stream>>>(wih_f, wih_r, wihp);
    packwhh_kernel<<<8192, 256, 0, stream>>>(whh_f, whh_r, whhb);
    misc_kernel<<<16, 256, 0, stream>>>(bih_f, bhh_f, bih_r, bhh_r, bsum);

    // conv GEMMs (two launches: per-launch B panel fits per-XCD L2)
    gemm_bf16<0><<<63 * 8, 256, 0, stream>>>(xbf, W1, G1, 8032, 1024, 10240, 1024,
                                             502, 512u * 2048u, 2048u, 0u);
    gemm_bf16<0><<<63 * 8, 256, 0, stream>>>(xbf, W2, G2, 8032, 1024, 10240, 1024,
                                             502, 512u * 2048u, 2048u, 5u * 2048u);
    // seq build
    combine_kernel<<<8032, 256, 0, stream>>>(G1, G2, bb, ba, br, seqp);
    // input projections: M=8032 (t*16+b), K=576, N=4096 -> bf16 P (grid 2016 = 8*252)
    gemm_bf16<1><<<63 * 32, 256, 0, stream>>>(seqp, wihp, Pb, 8032, 4096, 576, 4096,
                                              8032, 0u, 576u, 0u);
    // publication-copy tag init (G region now dead)
    hbinit_kernel<<<256, 256, 0, stream>>>(hbig);
    // recurrence: R11 config + 4-copy publish spread
    lstm_kernel<<<32, 256, 0, stream>>>(Pb, whhb, bsum, hbig, hs);
    // output
    final_kernel<<<8032, 256, 0, stream>>>(hs, wfc, bfc, out);
}

// Round 15
// 1677.280 us; speedup vs baseline: 1.1266x; 1.0622x over previous
//
#include <hip/hip_runtime.h>
#include <hip/hip_bf16.h>

typedef short v8s __attribute__((ext_vector_type(8)));
typedef float v4f __attribute__((ext_vector_type(4)));
typedef unsigned int u32;
typedef unsigned int u32x4 __attribute__((ext_vector_type(4)));
typedef unsigned short u16;
typedef unsigned long long u64;

// ---------- helpers ----------
__device__ __forceinline__ u16 f2bf(float f) {
    union { float f; u32 u; } x; x.f = f;
    u32 r = x.u + 0x7fffu + ((x.u >> 16) & 1u);   // RNE
    return (u16)(r >> 16);
}
__device__ __forceinline__ float bf2f(u16 s) {
    union { u32 u; float f; } x; x.u = ((u32)s) << 16;
    return x.f;
}
__device__ __forceinline__ float sigmoidf_(float x) { return 1.f / (1.f + __expf(-x)); }
__device__ __forceinline__ float tanh_fast(float x) {
    float t = fminf(fmaxf(x, -15.f), 15.f);
    float e = __expf(2.f * t);
    return (e - 1.f) / (e + 1.f);
}

// ---------- prep kernels ----------
__global__ __launch_bounds__(256) void xbf_kernel(const float* __restrict__ x, u16* __restrict__ xbf, int n) {
    int i = (blockIdx.x * 256 + threadIdx.x) * 4;
    if (i + 3 < n) {
        float4 v = *(const float4*)(x + i);
        u16* d = xbf + i;
        d[0] = f2bf(v.x); d[1] = f2bf(v.y); d[2] = f2bf(v.z); d[3] = f2bf(v.w);
    }
}

// W1[n][tap*2048+d] = n<512 ? wb[n,d,tap] : wr[n-512,d,tap]
// W2[n][tap*2048+d] = n<512 ? wa[n,d,tap] : wr[n-512,d,tap+5]
__global__ __launch_bounds__(256) void packw_kernel(const float* __restrict__ wb, const float* __restrict__ wa,
                                                    const float* __restrict__ wr, u16* __restrict__ W1, u16* __restrict__ W2) {
    long e = ((long)blockIdx.x * 256 + threadIdx.x) * 4;    // < 2*1024*10240
    int which = e >= (1024L * 10240) ? 1 : 0;
    long rem = e - (long)which * 1024 * 10240;
    int n = (int)(rem / 10240);
    int kap = (int)(rem % 10240);
    int tap = kap >> 11, d = kap & 2047;
    u16 o[4];
    if (n < 512) {
        const float* src = which ? wa : wb;
#pragma unroll
        for (int q = 0; q < 4; ++q) o[q] = f2bf(src[(long)n * 10240 + (d + q) * 5 + tap]);
    } else {
        const float* src = wr + (long)(n - 512) * 20480 + tap + (which ? 5 : 0);
#pragma unroll
        for (int q = 0; q < 4; ++q) o[q] = f2bf(src[(d + q) * 10]);
    }
    *(u64*)((which ? W2 : W1) + rem) = *(const u64*)o;
}

// wihpad[(dir*2048+g)][k] (K padded 513->576)
__global__ __launch_bounds__(256) void packwih_kernel(const float* __restrict__ wf, const float* __restrict__ wr,
                                                      u16* __restrict__ Bp) {
    int idx = blockIdx.x * 256 + threadIdx.x;               // < 4096*576
    int n = idx / 576, kap = idx % 576;
    int dir = n >> 11, g = n & 2047;
    const float* src = dir ? wr : wf;
    float v = (kap < 513) ? src[(long)g * 513 + kap] : 0.f;
    Bp[idx] = f2bf(v);
}

__global__ __launch_bounds__(256) void packwhh_kernel(const float* __restrict__ whf, const float* __restrict__ whr,
                                                      u16* __restrict__ W) {
    int idx = blockIdx.x * 256 + threadIdx.x;               // < 2*2048*512 = 2^21
    int dir = idx >> 20;
    float v = dir ? whr[idx & 1048575] : whf[idx];
    W[idx] = f2bf(v);
}

// bsum + hbuf tag clear (must run every launch: graph replays reuse hbuf)
__global__ __launch_bounds__(256) void misc_kernel(const float* __restrict__ bihf, const float* __restrict__ bhhf,
                                                   const float* __restrict__ bihr, const float* __restrict__ bhhr,
                                                   float* __restrict__ bsum, u64* __restrict__ hbuf) {
    int i = blockIdx.x * 256 + threadIdx.x;                 // grid covers 4096 + 16384
    if (i < 2048) bsum[i] = bihf[i] + bhhf[i];
    else if (i < 4096) bsum[i] = bihr[i - 2048] + bhhr[i - 2048];
    else if (i < 4096 + 16384) hbuf[i - 4096] = 0xFFFFFFFF00000000ULL;
}

// ---------- deep-pipelined conv GEMM: C(8032x1024,f32) = A(im2col bf16) * W(1024x10240)^T ----------
// BM=256 BN=128 BK=32, 512 thr / 8 waves (wave 64x64), 4 LDS slots, prefetch 3 K-tiles ahead,
// counted vmcnt(6) across barriers (never 0 in steady state). tn = bid&7 pins each B-panel
// to one XCD's L2. Pair-packed XOR LDS layout: logical (row, kbyte<64) ->
// (row>>1)*128 + ((((row&1)<<6)|kbyte) ^ (((row>>1)&7)<<4))  — uniform 2-way banks (free).
__global__ __launch_bounds__(512, 1) void gemm_conv(const u16* __restrict__ A, const u16* __restrict__ B,
                                                    float* __restrict__ C, u32 row_base) {
    const int M = 8032, K = 10240, NT = 320;
    __shared__ char lds[98304];             // A: 4 slots x 16KB @0 ; B: 4 slots x 8KB @65536
    const int tn = blockIdx.x & 7;          // XCD-pinned B panel
    const int tm = blockIdx.x >> 3;         // 0..31
    const int tid = threadIdx.x, lane = tid & 63, w = tid >> 6;
    const int wm = w >> 1, wn = w & 1;
    const int lane15 = lane & 15, kgrp = lane >> 4;

    // staging source offsets (elements): thread t covers LDS bytes r*8192 + t*16 (A), t*16 (B)
    u32 asrc[2], bsrc;
#pragma unroll
    for (int r = 0; r < 2; ++r) {
        int l = r * 8192 + tid * 16;
        int rp = l >> 7, inner = l & 127;
        int innp = inner ^ ((rp & 7) << 4);
        int row = rp * 2 + (innp >> 6);
        int kb = innp & 63;
        int m = tm * 256 + row; if (m > M - 1) m = M - 1;
        asrc[r] = row_base + (u32)(m / 502) * (512u * 2048u) + (u32)(m % 502) * 2048u + (u32)(kb >> 1);
    }
    {
        int l = tid * 16;
        int rp = l >> 7, inner = l & 127;
        int innp = inner ^ ((rp & 7) << 4);
        int row = rp * 2 + (innp >> 6);
        int kb = innp & 63;
        bsrc = (u32)(tn * 128 + row) * (u32)K + (u32)(kb >> 1);
    }
    // fragment read offsets (read side of the same layout)
    int aoff[4], boff[4];
#pragma unroll
    for (int i = 0; i < 4; ++i) {
        int row = wm * 64 + i * 16 + lane15;
        int rp = row >> 1;
        aoff[i] = rp * 128 + ((((row & 1) << 6) | (kgrp * 16)) ^ ((rp & 7) << 4));
        int rowb = wn * 64 + i * 16 + lane15;
        int rpb = rowb >> 1;
        boff[i] = rpb * 128 + ((((rowb & 1) << 6) | (kgrp * 16)) ^ ((rpb & 7) << 4));
    }

    v4f acc[4][4];
#pragma unroll
    for (int i = 0; i < 4; ++i)
#pragma unroll
        for (int j = 0; j < 4; ++j) acc[i][j] = (v4f){0.f, 0.f, 0.f, 0.f};

#define ISSUE(t) {                                                                          \
        int s_ = (t) & 3;                                                                   \
        __builtin_amdgcn_global_load_lds(                                                   \
            (const __attribute__((address_space(1))) u32*)(A + asrc[0] + (t) * 32),         \
            (__attribute__((address_space(3))) u32*)(lds + s_ * 16384 + w * 1024), 16, 0, 0);\
        __builtin_amdgcn_global_load_lds(                                                   \
            (const __attribute__((address_space(1))) u32*)(A + asrc[1] + (t) * 32),         \
            (__attribute__((address_space(3))) u32*)(lds + s_ * 16384 + 8192 + w * 1024), 16, 0, 0);\
        __builtin_amdgcn_global_load_lds(                                                   \
            (const __attribute__((address_space(1))) u32*)(B + bsrc + (t) * 32),            \
            (__attribute__((address_space(3))) u32*)(lds + 65536 + s_ * 8192 + w * 1024), 16, 0, 0);\
    }

    // prologue: stage tiles 0,1,2; wait for tile 0 (keep 6 loads = tiles 1,2 in flight)
    ISSUE(0) ISSUE(1) ISSUE(2)
    asm volatile("s_waitcnt vmcnt(6)" ::: "memory");
    __builtin_amdgcn_s_barrier();
    asm volatile("" ::: "memory");

    for (int kt = 0; kt < NT; ++kt) {
        const char* As = lds + (kt & 3) * 16384;
        const char* Bs = lds + 65536 + (kt & 3) * 8192;
        v8s a[4], b[4];
#pragma unroll
        for (int i = 0; i < 4; ++i) {
            a[i] = *(const v8s*)(As + aoff[i]);
            b[i] = *(const v8s*)(Bs + boff[i]);
        }
        if (kt + 3 < NT) ISSUE(kt + 3)      // overwrites slot of tile kt-1 (readers done at last barrier)
        __builtin_amdgcn_s_setprio(1);
#pragma unroll
        for (int i = 0; i < 4; ++i)
#pragma unroll
            for (int j = 0; j < 4; ++j)
                acc[i][j] = __builtin_amdgcn_mfma_f32_16x16x32_bf16(a[i], b[j], acc[i][j], 0, 0, 0);
        __builtin_amdgcn_s_setprio(0);
        // wait only until tile kt+1 is resident; tiles kt+2, kt+3 stay in flight
        if (kt + 3 < NT)      { asm volatile("s_waitcnt vmcnt(6)" ::: "memory"); }
        else if (kt + 2 < NT) { asm volatile("s_waitcnt vmcnt(3)" ::: "memory"); }
        else                  { asm volatile("s_waitcnt vmcnt(0)" ::: "memory"); }
        __builtin_amdgcn_s_barrier();
        asm volatile("" ::: "memory");
    }
#undef ISSUE

#pragma unroll
    for (int i = 0; i < 4; ++i)
#pragma unroll
        for (int j = 0; j < 4; ++j)
#pragma unroll
            for (int r = 0; r < 4; ++r) {
                int m = tm * 256 + wm * 64 + i * 16 + kgrp * 4 + r;
                int n = tn * 128 + wn * 64 + j * 16 + lane15;
                if (m < M) C[(long)m * 1024 + n] = acc[i][j][r];
            }
}

// ---------- bf16 GEMM (proj): C(MxN) = A(MxK) * B(NxK)^T, bf16 out ----------
template <int OUTBF>
__global__ __launch_bounds__(256) void gemm_bf16(const u16* __restrict__ A, const u16* __restrict__ B,
                                                 void* __restrict__ Cv, int M, int N, int K, int ldc,
                                                 int row_div, u32 row_mul1, u32 row_mul2, u32 row_base) {
    __shared__ u16 ldsA[128 * 64];
    __shared__ u16 ldsB[128 * 64];
    const int ntn = N >> 7;
    const int nwg = gridDim.x;
    const int bid = blockIdx.x;
    const int swz = (bid & 7) * (nwg >> 3) + (bid >> 3);
    const int tm = swz / ntn, tn = swz % ntn;
    const int tid = threadIdx.x, lane = tid & 63, wv = tid >> 6;
    const int wm = wv >> 1, wn = wv & 1;
    const int qbase = wv * 4;

    u32 asrc[4], bsrc[4];
#pragma unroll
    for (int it = 0; it < 4; ++it) {
        int q = qbase + it;
        int r = q * 8 + (lane >> 3);
        int cb = ((lane & 7) * 16) ^ ((r & 7) << 4);
        int m = tm * 128 + r; if (m > M - 1) m = M - 1;
        asrc[it] = row_base + (u32)(m / row_div) * row_mul1 + (u32)(m % row_div) * row_mul2 + (u32)(cb >> 1);
        int n = tn * 128 + r;
        bsrc[it] = (u32)n * (u32)K + (u32)(cb >> 1);
    }

    v4f acc[4][4];
#pragma unroll
    for (int i = 0; i < 4; ++i)
#pragma unroll
        for (int j = 0; j < 4; ++j) acc[i][j] = (v4f){0.f, 0.f, 0.f, 0.f};

    const int KT = K >> 6;
    for (int kt = 0; kt < KT; ++kt) {
        const int k0 = kt << 6;
#pragma unroll
        for (int it = 0; it < 4; ++it) {
            int q = qbase + it;
            __builtin_amdgcn_global_load_lds(
                (const __attribute__((address_space(1))) u32*)(A + asrc[it] + k0),
                (__attribute__((address_space(3))) u32*)((char*)ldsA + q * 1024), 16, 0, 0);
            __builtin_amdgcn_global_load_lds(
                (const __attribute__((address_space(1))) u32*)(B + bsrc[it] + k0),
                (__attribute__((address_space(3))) u32*)((char*)ldsB + q * 1024), 16, 0, 0);
        }
        __syncthreads();
#pragma unroll
        for (int kk = 0; kk < 2; ++kk) {
            v8s af[4], bfr[4];
#pragma unroll
            for (int i = 0; i < 4; ++i) {
                int row = wm * 64 + i * 16 + (lane & 15);
                int cbyte = (kk * 64 + ((lane >> 4) * 16)) ^ ((row & 7) << 4);
                af[i] = *(const v8s*)((const char*)ldsA + row * 128 + cbyte);
                int rn = wn * 64 + i * 16 + (lane & 15);
                int cbn = (kk * 64 + ((lane >> 4) * 16)) ^ ((rn & 7) << 4);
                bfr[i] = *(const v8s*)((const char*)ldsB + rn * 128 + cbn);
            }
#pragma unroll
            for (int i = 0; i < 4; ++i)
#pragma unroll
                for (int j = 0; j < 4; ++j)
                    acc[i][j] = __builtin_amdgcn_mfma_f32_16x16x32_bf16(af[i], bfr[j], acc[i][j], 0, 0, 0);
        }
        __syncthreads();
    }
#pragma unroll
    for (int i = 0; i < 4; ++i)
#pragma unroll
        for (int j = 0; j < 4; ++j)
#pragma unroll
            for (int r = 0; r < 4; ++r) {
                int m = tm * 128 + wm * 64 + i * 16 + (lane >> 4) * 4 + r;
                int n = tn * 128 + wn * 64 + j * 16 + (lane & 15);
                if (m < M) {
                    if (OUTBF) ((u16*)Cv)[(long)m * ldc + n] = f2bf(acc[i][j][r]);
                    else       ((float*)Cv)[(long)m * ldc + n] = acc[i][j][r];
                }
            }
}

// ---------- combine: build seq (bf16, padded K=576, row = t*16+b) ----------
__global__ __launch_bounds__(256) void combine_kernel(const float* __restrict__ G1, const float* __restrict__ G2,
                                                      const float* __restrict__ bb, const float* __restrict__ ba,
                                                      const float* __restrict__ br, u16* __restrict__ seqpad) {
    int m = blockIdx.x;                    // b*502 + t
    int b = m / 502, t = m % 502;
    int tid = threadIdx.x;
    const float* g1 = G1 + (long)m * 1024;
    const float* g2 = G2 + (long)m * 1024;
    u16* dst = seqpad + (long)(t * 16 + b) * 576;
    float part = 0.f;
#pragma unroll
    for (int rep = 0; rep < 2; ++rep) {
        int u = tid + rep * 256;
        float db = g1[u] + bb[u];
        float da = g2[u] + ba[u];
        part += db * da;
        float vr = g1[512 + u] + g2[512 + u] + br[u];
        dst[u] = f2bf(vr);
    }
#pragma unroll
    for (int off = 32; off; off >>= 1) part += __shfl_down(part, off, 64);
    __shared__ float red[4];
    if ((tid & 63) == 0) red[tid >> 6] = part;
    __syncthreads();
    if (tid == 0) dst[512] = f2bf(red[0] + red[1] + red[2] + red[3]);
    if (tid >= 1 && tid < 64) dst[512 + tid] = 0;
}

// ---------- persistent bidirectional LSTM (R11 configuration — proven 1147us floor) ----------
__global__ __launch_bounds__(256, 1) void lstm_kernel(const u16* __restrict__ P, const u16* __restrict__ whhbf,
                                                      const float* __restrict__ bsum, u64* hbuf,
                                                      u16* __restrict__ hs) {
    const int wg = blockIdx.x;
    const int dir = wg >> 4, j = wg & 15;
    const int tid = threadIdx.x, lane = tid & 63, w = tid >> 6;
    __shared__ u16 hls[16 * 512];          // h (batch x 512) bf16, XOR-swizzled rows
    __shared__ float gls[4][16][32];       // gate type x batch x unit

    v8s bf[2][16];                          // whh^T fragments resident all 502 steps
    const u16* whd = whhbf + (long)dir * 2048 * 512;
#pragma unroll
    for (int nt = 0; nt < 2; ++nt) {
        int n = w * 512 + j * 32 + nt * 16 + (lane & 15);
#pragma unroll
        for (int kt = 0; kt < 16; ++kt)
            bf[nt][kt] = *(const v8s*)(whd + (long)n * 512 + kt * 32 + ((lane >> 4) * 8));
    }

    for (int i = tid; i < 8192; i += 256) hls[i] = 0;

    const int b_ = tid >> 4;
    const int u_ = (tid * 2) & 31;
    float c0 = 0.f, c1 = 0.f;
    u64* hb = hbuf + dir * 2 * 4096;
    const int col0 = w * 512 + j * 32 + (lane & 15);
    const float bs0 = bsum[dir * 2048 + col0];
    const float bs1 = bsum[dir * 2048 + col0 + 16];
    const u16* Pd = P + dir * 2048;

    // prefetch P for s=0
    float pv[2][4];
    {
        int tau = dir ? 501 : 0;
#pragma unroll
        for (int nt = 0; nt < 2; ++nt)
#pragma unroll
            for (int r = 0; r < 4; ++r)
                pv[nt][r] = bf2f(Pd[(long)(tau * 16 + ((lane >> 4) * 4 + r)) * 4096 + col0 + nt * 16]);
    }
    __syncthreads();

    for (int s = 0; s < 502; ++s) {
        const int tau = dir ? (501 - s) : s;
        if (s > 0) {
            const u64* slotp = hb + ((s - 1) & 1) * 4096;
            const u32 want = (u32)(s - 1);
            u64 base = (u64)slotp + (u64)tid * 16;           // thread reads words tid*2 + rep*512 (+0/1)
            u64 a0 = base,          a1 = base + 4096,  a2 = base + 8192,  a3 = base + 12288;
            u64 a4 = base + 16384,  a5 = base + 20480, a6 = base + 24576, a7 = base + 28672;
            u32x4 w0, w1, w2, w3, w4, w5, w6, w7;
            for (;;) {
                asm volatile(
                    "global_load_dwordx4 %[w0], %[a0], off sc1\n\t"
                    "global_load_dwordx4 %[w1], %[a1], off sc1\n\t"
                    "global_load_dwordx4 %[w2], %[a2], off sc1\n\t"
                    "global_load_dwordx4 %[w3], %[a3], off sc1\n\t"
                    "global_load_dwordx4 %[w4], %[a4], off sc1\n\t"
                    "global_load_dwordx4 %[w5], %[a5], off sc1\n\t"
                    "global_load_dwordx4 %[w6], %[a6], off sc1\n\t"
                    "global_load_dwordx4 %[w7], %[a7], off sc1\n\t"
                    "s_waitcnt vmcnt(0)"
                    : [w0]"=v"(w0), [w1]"=v"(w1), [w2]"=v"(w2), [w3]"=v"(w3),
                      [w4]"=v"(w4), [w5]"=v"(w5), [w6]"=v"(w6), [w7]"=v"(w7)
                    : [a0]"v"(a0), [a1]"v"(a1), [a2]"v"(a2), [a3]"v"(a3),
                      [a4]"v"(a4), [a5]"v"(a5), [a6]"v"(a6), [a7]"v"(a7)
                    : "memory");
                u32 ok = (w0[1] == want) + (w0[3] == want) + (w1[1] == want) + (w1[3] == want)
                       + (w2[1] == want) + (w2[3] == want) + (w3[1] == want) + (w3[3] == want)
                       + (w4[1] == want) + (w4[3] == want) + (w5[1] == want) + (w5[3] == want)
                       + (w6[1] == want) + (w6[3] == want) + (w7[1] == want) + (w7[3] == want);
                if (ok == 16) break;
            }
#define FILL(rep, pay0, pay1) {                                                             \
            int i0 = tid * 2 + (rep) * 512;                                                 \
            int bb2 = i0 >> 8; int p = i0 & 255;                                            \
            int bo = (bb2 << 10) + ((p << 2) ^ ((bb2 & 7) << 4));                           \
            *(u32*)((char*)hls + bo) = (pay0);                                              \
            int p1 = p + 1;                                                                 \
            int bo1 = (bb2 << 10) + ((p1 << 2) ^ ((bb2 & 7) << 4));                         \
            *(u32*)((char*)hls + bo1) = (pay1); }
            FILL(0, w0[0], w0[2]) FILL(1, w1[0], w1[2]) FILL(2, w2[0], w2[2]) FILL(3, w3[0], w3[2])
            FILL(4, w4[0], w4[2]) FILL(5, w5[0], w5[2]) FILL(6, w6[0], w6[2]) FILL(7, w7[0], w7[2])
#undef FILL
        }
        __syncthreads();                                    // B1: hls ready
        v4f a0a, a1a, a0b = (v4f){0, 0, 0, 0}, a1b = (v4f){0, 0, 0, 0};
#pragma unroll
        for (int r = 0; r < 4; ++r) { a0a[r] = pv[0][r] + bs0; a1a[r] = pv[1][r] + bs1; }
#pragma unroll
        for (int kt = 0; kt < 16; kt += 2) {
            int row = lane & 15;
            int cb0 = (kt * 64 + ((lane >> 4) * 16)) ^ ((row & 7) << 4);
            int cb1 = ((kt + 1) * 64 + ((lane >> 4) * 16)) ^ ((row & 7) << 4);
            v8s af0 = *(const v8s*)((const char*)hls + row * 1024 + cb0);
            v8s af1 = *(const v8s*)((const char*)hls + row * 1024 + cb1);
            a0a = __builtin_amdgcn_mfma_f32_16x16x32_bf16(af0, bf[0][kt], a0a, 0, 0, 0);
            a1a = __builtin_amdgcn_mfma_f32_16x16x32_bf16(af0, bf[1][kt], a1a, 0, 0, 0);
            a0b = __builtin_amdgcn_mfma_f32_16x16x32_bf16(af1, bf[0][kt + 1], a0b, 0, 0, 0);
            a1b = __builtin_amdgcn_mfma_f32_16x16x32_bf16(af1, bf[1][kt + 1], a1b, 0, 0, 0);
        }
#pragma unroll
        for (int r = 0; r < 4; ++r) {
            gls[w][(lane >> 4) * 4 + r][(lane & 15)] = a0a[r] + a0b[r];
            gls[w][(lane >> 4) * 4 + r][16 + (lane & 15)] = a1a[r] + a1b[r];
        }
        __syncthreads();                                    // B2: gls ready (protects hls reuse)
        float i0 = gls[0][b_][u_],     f0 = gls[1][b_][u_],     g0 = gls[2][b_][u_],     o0 = gls[3][b_][u_];
        float i1 = gls[0][b_][u_ + 1], f1 = gls[1][b_][u_ + 1], g1v = gls[2][b_][u_ + 1], o1 = gls[3][b_][u_ + 1];
        c0 = sigmoidf_(f0) * c0 + sigmoidf_(i0) * tanh_fast(g0);
        c1 = sigmoidf_(f1) * c1 + sigmoidf_(i1) * tanh_fast(g1v);
        float h0 = sigmoidf_(o0) * tanh_fast(c0);
        float h1 = sigmoidf_(o1) * tanh_fast(c1);
        u32 hw = (u32)f2bf(h0) | ((u32)f2bf(h1) << 16);
        int gi = (b_ * 512 + j * 32 + u_) >> 1;
        __hip_atomic_store(hb + (s & 1) * 4096 + gi, (u64)hw | ((u64)(u32)s << 32),
                           __ATOMIC_RELAXED, __HIP_MEMORY_SCOPE_AGENT);
        *(u32*)(hs + (((long)(dir * 502 + tau) * 16 + b_) * 512 + j * 32 + u_)) = hw;
        if (s + 1 < 502) {
            int tau2 = dir ? (500 - s) : (s + 1);
#pragma unroll
            for (int nt = 0; nt < 2; ++nt)
#pragma unroll
                for (int r = 0; r < 4; ++r)
                    pv[nt][r] = bf2f(Pd[(long)(tau2 * 16 + ((lane >> 4) * 4 + r)) * 4096 + col0 + nt * 16]);
        }
    }
}

// ---------- final FC + sigmoid ----------
__global__ __launch_bounds__(256) void final_kernel(const u16* __restrict__ hs, const float* __restrict__ wfc,
                                                    const float* __restrict__ bfc, float* __restrict__ out) {
    int m = blockIdx.x;                    // t*16 + b
    int t = m >> 4, b = m & 15;
    int tid = threadIdx.x;
    const u16* hf = hs + ((long)t * 16 + b) * 512;
    const u16* hr = hs + ((long)(502 + t) * 16 + b) * 512;
    float part = 0.f;
#pragma unroll
    for (int rep = 0; rep < 2; ++rep) {
        int u = tid + rep * 256;
        part += bf2f(hf[u]) * wfc[u] + bf2f(hr[u]) * wfc[512 + u];
    }
#pragma unroll
    for (int off = 32; off; off >>= 1) part += __shfl_down(part, off, 64);
    __shared__ float red[4];
    if ((tid & 63) == 0) red[tid >> 6] = part;
    __syncthreads();
    if (tid == 0) {
        float lg = red[0] + red[1] + red[2] + red[3] + bfc[0];
        out[(long)b * 502 + t] = 1.f / (1.f + __expf(-lg));
    }
}

// ---------- launch ----------
extern "C" void kernel_launch(void* const* d_in, const int* in_sizes, int n_in,
                              void* d_out, int out_size, void* d_ws, size_t ws_size,
                              hipStream_t stream) {
    const float* x     = (const float*)d_in[0];
    const float* wb    = (const float*)d_in[1];
    const float* bb    = (const float*)d_in[2];
    const float* wa    = (const float*)d_in[3];
    const float* ba    = (const float*)d_in[4];
    const float* wr    = (const float*)d_in[5];
    const float* br    = (const float*)d_in[6];
    const float* wih_f = (const float*)d_in[7];
    const float* whh_f = (const float*)d_in[8];
    const float* bih_f = (const float*)d_in[9];
    const float* bhh_f = (const float*)d_in[10];
    const float* wih_r = (const float*)d_in[11];
    const float* whh_r = (const float*)d_in[12];
    const float* bih_r = (const float*)d_in[13];
    const float* bhh_r = (const float*)d_in[14];
    const float* wfc   = (const float*)d_in[15];
    const float* bfc   = (const float*)d_in[16];
    float* out = (float*)d_out;

    char* ws = (char*)d_ws;
    // Region 1: xbf | W1 | W2 -> dead after conv GEMMs, reused for Pb
    u16* xbf = (u16*)ws;
    u16* W1  = (u16*)(ws + 33554432);
    u16* W2  = (u16*)(ws + 54525952);
    u16* Pb  = (u16*)ws;
    // Region 2: G1 | G2 -> dead after combine, reused for hs
    char* r2 = ws + 75497472;
    float* G1 = (float*)r2;
    float* G2 = (float*)(r2 + 32899072);
    u16*  hs  = (u16*)r2;
    // Region 3: persistent smalls
    char* r3 = r2 + 65798144;
    u16*  seqp = (u16*)r3;                    //  9,252,864
    u16*  wihp = (u16*)(r3 + 9252864);        //  4,718,592
    u16*  whhb = (u16*)(r3 + 13971456);       //  4,194,304
    float* bsum= (float*)(r3 + 18165760);     //     16,384
    u64*  hbuf = (u64*)(r3 + 18182144);       //    131,072 (2 dir x 2 slot x 4096 x 8B)

    // prep
    xbf_kernel<<<16384, 256, 0, stream>>>(x, xbf, 16 * 512 * 2048);
    packw_kernel<<<20480, 256, 0, stream>>>(wb, wa, wr, W1, W2);
    packwih_kernel<<<9216, 256, 0, stream>>>(wih_f, wih_r, wihp);
    packwhh_kernel<<<8192, 256, 0, stream>>>(whh_f, whh_r, whhb);
    misc_kernel<<<80, 256, 0, stream>>>(bih_f, bhh_f, bih_r, bhh_r, bsum, hbuf);

    // conv GEMMs: deep-pipelined (counted vmcnt, 3-tile prefetch), 256 blocks x 512 thr each
    gemm_conv<<<256, 512, 0, stream>>>(xbf, W1, G1, 0u);
    gemm_conv<<<256, 512, 0, stream>>>(xbf, W2, G2, 5u * 2048u);
    // seq build
    combine_kernel<<<8032, 256, 0, stream>>>(G1, G2, bb, ba, br, seqp);
    // input projections: M=8032 (t*16+b), K=576, N=4096 -> bf16 P (grid 2016 = 8*252)
    gemm_bf16<1><<<63 * 32, 256, 0, stream>>>(seqp, wihp, Pb, 8032, 4096, 576, 4096,
                                              8032, 0u, 576u, 0u);
    // recurrence: R11 configuration (proven floor)
    lstm_kernel<<<32, 256, 0, stream>>>(Pb, whhb, bsum, hbuf, hs);
    // output
    final_kernel<<<8032, 256, 0, stream>>>(hs, wfc, bfc, out);
}